// Round 1
// baseline (888.863 us; speedup 1.0000x reference)
//
#include <hip/hip_runtime.h>
#include <hip/hip_bf16.h>
#include <math.h>

#define B_    2
#define NPTS_ 32768
#define T_    32768
#define P_    512
#define C_    4
#define D_    768
#define M_    (B_ * T_)   // 65536

typedef __bf16 bf16_t;
typedef __bf16 bf16x8 __attribute__((ext_vector_type(8)));
typedef float  f32x4  __attribute__((ext_vector_type(4)));

__device__ inline void gload16(const void* g, void* l) {
  __builtin_amdgcn_global_load_lds(
      (const __attribute__((address_space(1))) void*)g,
      (__attribute__((address_space(3))) void*)l, 16, 0, 0);
}

__device__ inline float gelu_exact(float x) {
  return 0.5f * x * (1.0f + erff(x * 0.70710678118654752f));
}

// ---------------- seg[t] = segment id via binary search ----------------
__global__ void seg_kernel(const int* __restrict__ off, int* __restrict__ seg) {
  int t = blockIdx.x * blockDim.x + threadIdx.x;
  if (t >= T_) return;
  int lo = 0, hi = P_;
  while (lo < hi) {
    int mid = (lo + hi) >> 1;
    if (off[mid + 1] <= t) lo = mid + 1; else hi = mid;
  }
  seg[t] = lo;
}

// ------------- weight convert fp32 [K][N] -> bf16 [N][K] (B^T) --------
__global__ void wconv_kernel(const float* __restrict__ src, bf16_t* __restrict__ dst,
                             int K, int N) {
  int i = blockIdx.x * blockDim.x + threadIdx.x;
  if (i >= K * N) return;
  int n = i / K, k = i - n * K;
  dst[i] = (bf16_t)src[(size_t)k * N + n];
}

// -------- fused: gather latent -> @w1a + b1a -> LN(1e-6) -> gelu -> bf16
__global__ __launch_bounds__(256) void embed_kernel(
    const float4* __restrict__ latent4, const int* __restrict__ pidx,
    const float* __restrict__ w1a, const float* __restrict__ b1a,
    bf16_t* __restrict__ act1) {
  int m = blockIdx.x;                 // 0..M_-1
  int b = m >> 15, t = m & (T_ - 1);
  int tid = threadIdx.x;
  float4 x = latent4[(size_t)b * NPTS_ + pidx[t]];
  float v[3];
  #pragma unroll
  for (int s = 0; s < 3; ++s) {
    int d = tid + s * 256;
    v[s] = b1a[d] + x.x * w1a[d] + x.y * w1a[D_ + d]
                 + x.z * w1a[2 * D_ + d] + x.w * w1a[3 * D_ + d];
  }
  float sum = v[0] + v[1] + v[2];
  float sq  = v[0]*v[0] + v[1]*v[1] + v[2]*v[2];
  #pragma unroll
  for (int o = 32; o > 0; o >>= 1) { sum += __shfl_down(sum, o); sq += __shfl_down(sq, o); }
  __shared__ float rs[4], rq[4], stats[2];
  int wid = tid >> 6, lane = tid & 63;
  if (lane == 0) { rs[wid] = sum; rq[wid] = sq; }
  __syncthreads();
  if (tid == 0) {
    float S = rs[0] + rs[1] + rs[2] + rs[3];
    float Q = rq[0] + rq[1] + rq[2] + rq[3];
    float mu = S * (1.0f / D_);
    float var = Q * (1.0f / D_) - mu * mu;
    stats[0] = mu; stats[1] = rsqrtf(var + 1e-6f);
  }
  __syncthreads();
  float mu = stats[0], rstd = stats[1];
  size_t base = (size_t)m * D_;
  #pragma unroll
  for (int s = 0; s < 3; ++s) {
    float yv = (v[s] - mu) * rstd;
    act1[base + tid + s * 256] = (bf16_t)gelu_exact(yv);
  }
}

// -------- LN(1e-5, g2, beta2) + gelu on bf16 rows -> bf16 --------------
__global__ __launch_bounds__(256) void ln2_kernel(
    const bf16_t* __restrict__ h2pre, const float* __restrict__ g2,
    const float* __restrict__ beta2, bf16_t* __restrict__ act2) {
  int m = blockIdx.x, tid = threadIdx.x;
  size_t base = (size_t)m * D_;
  float v[3];
  #pragma unroll
  for (int s = 0; s < 3; ++s) v[s] = (float)h2pre[base + tid + s * 256];
  float sum = v[0] + v[1] + v[2];
  float sq  = v[0]*v[0] + v[1]*v[1] + v[2]*v[2];
  #pragma unroll
  for (int o = 32; o > 0; o >>= 1) { sum += __shfl_down(sum, o); sq += __shfl_down(sq, o); }
  __shared__ float rs[4], rq[4], stats[2];
  int wid = tid >> 6, lane = tid & 63;
  if (lane == 0) { rs[wid] = sum; rq[wid] = sq; }
  __syncthreads();
  if (tid == 0) {
    float S = rs[0] + rs[1] + rs[2] + rs[3];
    float Q = rq[0] + rq[1] + rq[2] + rq[3];
    float mu = S * (1.0f / D_);
    float var = Q * (1.0f / D_) - mu * mu;
    stats[0] = mu; stats[1] = rsqrtf(var + 1e-5f);
  }
  __syncthreads();
  float mu = stats[0], rstd = stats[1];
  #pragma unroll
  for (int s = 0; s < 3; ++s) {
    int d = tid + s * 256;
    float yv = (v[s] - mu) * rstd * g2[d] + beta2[d];
    act2[base + d] = (bf16_t)gelu_exact(yv);
  }
}

// -------- segment max over bf16 h -> bf16 y ----------------------------
__global__ __launch_bounds__(256) void segmax_kernel(
    const bf16_t* __restrict__ h, const int* __restrict__ off,
    bf16_t* __restrict__ y) {
  int bp = blockIdx.x;
  int b = bp >> 9, p = bp & (P_ - 1);
  int t0 = off[p], t1 = off[p + 1];
  int tid = threadIdx.x;
  const bf16_t* hb = h + (size_t)b * T_ * D_;
  #pragma unroll
  for (int s = 0; s < 3; ++s) {
    int d = tid + s * 256;
    float mx = -INFINITY;
    for (int t = t0; t < t1; ++t) mx = fmaxf(mx, (float)hb[(size_t)t * D_ + d]);
    y[(size_t)bp * D_ + d] = (bf16_t)mx;
  }
}

// -------- final: segmax(raw fp32) + pos_embed -> out fp32 --------------
__global__ __launch_bounds__(256) void final_kernel(
    const float* __restrict__ raw, const int* __restrict__ off,
    const float* __restrict__ pe, float* __restrict__ out) {
  int bp = blockIdx.x;
  int b = bp >> 9, p = bp & (P_ - 1);
  int t0 = off[p], t1 = off[p + 1];
  int tid = threadIdx.x;
  const float* rb = raw + (size_t)b * T_ * D_;
  #pragma unroll
  for (int s = 0; s < 3; ++s) {
    int d = tid + s * 256;
    float mx = -INFINITY;
    for (int t = t0; t < t1; ++t) mx = fmaxf(mx, rb[(size_t)t * D_ + d]);
    out[(size_t)bp * D_ + d] = mx + pe[(size_t)p * D_ + d];
  }
}

// -------- bf16 MFMA GEMM: C[M,N] = A[M,K] * BT[N,K]^T + bias -----------
// MODE 0: A from A ptr. MODE 1: A row m = concat(y[b, seg[t], :], h[m, :]).
template <int MODE, typename OutT>
__global__ __launch_bounds__(256) void gemm_kernel(
    const bf16_t* __restrict__ A, const bf16_t* __restrict__ BT,
    const float* __restrict__ bias, OutT* __restrict__ C,
    int M, int N, int K,
    const bf16_t* __restrict__ ybuf, const bf16_t* __restrict__ hbuf,
    const int* __restrict__ seg) {
  __shared__ bf16_t As[128 * 32];
  __shared__ bf16_t Bs[128 * 32];
  __shared__ int segm[128];
  int tid = threadIdx.x;
  int wave = tid >> 6, lane = tid & 63;
  int lr = lane & 15, hi = lane >> 4;
  int wm = wave >> 1, wn = wave & 1;
  int n0 = blockIdx.x * 128, m0 = blockIdx.y * 128;

  if (MODE == 1) {
    if (tid < 128) segm[tid] = seg[(m0 + tid) & (T_ - 1)];
  }

  f32x4 acc[4][4] = {};

  for (int kt = 0; kt < K; kt += 32) {
    __syncthreads();   // previous compute done (and segm visible on 1st iter)
    #pragma unroll
    for (int q = 0; q < 2; ++q) {
      int c = q * 256 + tid;
      int row = c >> 2, ko = (c & 3) * 8;
      const bf16_t* asrc;
      if (MODE == 0) {
        asrc = A + (size_t)(m0 + row) * K + (kt + ko);
      } else {
        int mrow = m0 + row;
        int kg = kt + ko;
        if (kg < D_)
          asrc = ybuf + ((size_t)((mrow >> 15) * P_ + segm[row])) * D_ + kg;
        else
          asrc = hbuf + (size_t)mrow * D_ + (kg - D_);
      }
      gload16(asrc, (char*)As + q * 4096 + wave * 1024);
      const bf16_t* bsrc = BT + (size_t)(n0 + row) * K + (kt + ko);
      gload16(bsrc, (char*)Bs + q * 4096 + wave * 1024);
    }
    __syncthreads();   // drains vmcnt before barrier

    bf16x8 af[4], bfr[4];
    #pragma unroll
    for (int i = 0; i < 4; ++i)
      af[i] = *reinterpret_cast<const bf16x8*>(&As[(size_t)(wm * 64 + i * 16 + lr) * 32 + hi * 8]);
    #pragma unroll
    for (int j = 0; j < 4; ++j)
      bfr[j] = *reinterpret_cast<const bf16x8*>(&Bs[(size_t)(wn * 64 + j * 16 + lr) * 32 + hi * 8]);
    #pragma unroll
    for (int i = 0; i < 4; ++i)
      #pragma unroll
      for (int j = 0; j < 4; ++j)
        acc[i][j] = __builtin_amdgcn_mfma_f32_16x16x32_bf16(af[i], bfr[j], acc[i][j], 0, 0, 0);
  }

  #pragma unroll
  for (int j = 0; j < 4; ++j) {
    int n = n0 + wn * 64 + j * 16 + lr;
    float bv = bias[n];
    #pragma unroll
    for (int i = 0; i < 4; ++i) {
      #pragma unroll
      for (int r = 0; r < 4; ++r) {
        int m = m0 + wm * 64 + i * 16 + hi * 4 + r;
        C[(size_t)m * N + n] = (OutT)(acc[i][j][r] + bv);
      }
    }
  }
}

extern "C" void kernel_launch(void* const* d_in, const int* in_sizes, int n_in,
                              void* d_out, int out_size, void* d_ws, size_t ws_size,
                              hipStream_t stream) {
  const float* latent       = (const float*)d_in[0];
  const int*   patch_index  = (const int*)d_in[1];
  const int*   patch_offset = (const int*)d_in[2];
  const float* pos_embed    = (const float*)d_in[3];
  const float* w1a  = (const float*)d_in[4];
  const float* b1a  = (const float*)d_in[5];
  const float* w1b  = (const float*)d_in[6];
  const float* b1b  = (const float*)d_in[7];
  const float* w2a  = (const float*)d_in[8];
  const float* b2a  = (const float*)d_in[9];
  const float* g2   = (const float*)d_in[10];
  const float* beta2= (const float*)d_in[11];
  const float* w2b  = (const float*)d_in[12];
  const float* b2b  = (const float*)d_in[13];

  float* out_f   = (float*)d_out;
  float* raw_out = out_f + (size_t)B_ * P_ * D_;

  char* ws = (char*)d_ws;
  size_t off = 0;
  auto take = [&](size_t bytes) {
    off = (off + 255) & ~(size_t)255;
    char* p = ws + off;
    off += bytes;
    return p;
  };
  int*    seg  = (int*)   take((size_t)T_ * 4);
  bf16_t* w1bT = (bf16_t*)take((size_t)D_ * D_ * 2);
  bf16_t* w2aT = (bf16_t*)take((size_t)2 * D_ * D_ * 2);
  bf16_t* w2bT = (bf16_t*)take((size_t)D_ * D_ * 2);
  bf16_t* ybuf = (bf16_t*)take((size_t)B_ * P_ * D_ * 2);
  bf16_t* bufY = (bf16_t*)take((size_t)M_ * D_ * 2);
  size_t needX = (size_t)M_ * D_ * 2;
  size_t offX  = (off + 255) & ~(size_t)255;
  bf16_t* bufX;
  if (offX + needX <= ws_size) {
    bufX = (bf16_t*)take(needX);
  } else {
    // fallback: stash act1/h2pre in d_out's raw_latent region (dead before
    // GEMM4 overwrites it with the real fp32 raw_latent).
    bufX = (bf16_t*)raw_out;
  }

  seg_kernel<<<(T_ + 255) / 256, 256, 0, stream>>>(patch_offset, seg);
  wconv_kernel<<<(D_ * D_ + 255) / 256, 256, 0, stream>>>(w1b, w1bT, D_, D_);
  wconv_kernel<<<(2 * D_ * D_ + 255) / 256, 256, 0, stream>>>(w2a, w2aT, 2 * D_, D_);
  wconv_kernel<<<(D_ * D_ + 255) / 256, 256, 0, stream>>>(w2b, w2bT, D_, D_);

  embed_kernel<<<M_, 256, 0, stream>>>((const float4*)latent, patch_index, w1a, b1a, bufX);

  gemm_kernel<0, bf16_t><<<dim3(D_ / 128, M_ / 128), 256, 0, stream>>>(
      bufX, w1bT, b1b, bufY, M_, D_, D_, nullptr, nullptr, nullptr);

  segmax_kernel<<<B_ * P_, 256, 0, stream>>>(bufY, patch_offset, ybuf);

  gemm_kernel<1, bf16_t><<<dim3(D_ / 128, M_ / 128), 256, 0, stream>>>(
      nullptr, w2aT, b2a, bufX, M_, D_, 2 * D_, ybuf, bufY, seg);

  ln2_kernel<<<M_, 256, 0, stream>>>(bufX, g2, beta2, bufY);

  gemm_kernel<0, float><<<dim3(D_ / 128, M_ / 128), 256, 0, stream>>>(
      bufY, w2bT, b2b, raw_out, M_, D_, D_, nullptr, nullptr, nullptr);

  final_kernel<<<B_ * P_, 256, 0, stream>>>(raw_out, patch_offset, pos_embed, out_f);
}

// Round 2
// 572.022 us; speedup vs baseline: 1.5539x; 1.5539x over previous
//
#include <hip/hip_runtime.h>
#include <hip/hip_bf16.h>
#include <math.h>

#define B_    2
#define NPTS_ 32768
#define T_    32768
#define P_    512
#define C_    4
#define D_    768
#define M_    (B_ * T_)   // 65536

typedef __bf16 bf16_t;
typedef __bf16 bf16x8 __attribute__((ext_vector_type(8)));
typedef __bf16 bf16x4 __attribute__((ext_vector_type(4)));
typedef float  f32x4  __attribute__((ext_vector_type(4)));

__device__ inline void gload16(const void* g, void* l) {
  __builtin_amdgcn_global_load_lds(
      (const __attribute__((address_space(1))) void*)g,
      (__attribute__((address_space(3))) void*)l, 16, 0, 0);
}

__device__ inline float gelu_exact(float x) {
  return 0.5f * x * (1.0f + erff(x * 0.70710678118654752f));
}

// ---------------- seg[t] = segment id via binary search ----------------
__global__ void seg_kernel(const int* __restrict__ off, int* __restrict__ seg) {
  int t = blockIdx.x * blockDim.x + threadIdx.x;
  if (t >= T_) return;
  int lo = 0, hi = P_;
  while (lo < hi) {
    int mid = (lo + hi) >> 1;
    if (off[mid + 1] <= t) lo = mid + 1; else hi = mid;
  }
  seg[t] = lo;
}

// ---- weight transpose fp32 [K][N] -> bf16 [N][K], LDS-tiled coalesced ----
__global__ __launch_bounds__(256) void wconvT_kernel(
    const float* __restrict__ src, bf16_t* __restrict__ dst, int K, int N) {
  __shared__ float tile[32][33];
  int n0 = blockIdx.x * 32, k0 = blockIdx.y * 32;
  int tx = threadIdx.x, ty = threadIdx.y;   // 32 x 8
  #pragma unroll
  for (int i = 0; i < 4; ++i)
    tile[ty + 8 * i][tx] = src[(size_t)(k0 + ty + 8 * i) * N + n0 + tx];
  __syncthreads();
  #pragma unroll
  for (int i = 0; i < 4; ++i)
    dst[(size_t)(n0 + ty + 8 * i) * K + k0 + tx] = (bf16_t)tile[tx][ty + 8 * i];
}

// -------- fused: gather latent -> @w1a + b1a -> LN(1e-6) -> gelu -> bf16
// one wave per row; lane owns 12 cols (8 @ lane*8, 4 @ 512+lane*4); no barriers
__global__ __launch_bounds__(256) void embed_kernel(
    const float4* __restrict__ latent4, const int* __restrict__ pidx,
    const float* __restrict__ w1a, const float* __restrict__ b1a,
    bf16_t* __restrict__ act1) {
  int wid = threadIdx.x >> 6, lane = threadIdx.x & 63;
  int m = blockIdx.x * 4 + wid;
  int b = m >> 15, t = m & (T_ - 1);
  float4 x = latent4[(size_t)b * NPTS_ + pidx[t]];
  int d8 = lane * 8, d4 = 512 + lane * 4;
  float v[12];
  {
    float4 a0 = *(const float4*)(b1a + d8);
    float4 a1 = *(const float4*)(b1a + d8 + 4);
    float4 a2 = *(const float4*)(b1a + d4);
    v[0]=a0.x; v[1]=a0.y; v[2]=a0.z; v[3]=a0.w;
    v[4]=a1.x; v[5]=a1.y; v[6]=a1.z; v[7]=a1.w;
    v[8]=a2.x; v[9]=a2.y; v[10]=a2.z; v[11]=a2.w;
  }
  float xk[4] = {x.x, x.y, x.z, x.w};
  #pragma unroll
  for (int k = 0; k < 4; ++k) {
    const float* w = w1a + k * D_;
    float4 w0 = *(const float4*)(w + d8);
    float4 w1 = *(const float4*)(w + d8 + 4);
    float4 w2 = *(const float4*)(w + d4);
    float f = xk[k];
    v[0] += f*w0.x; v[1] += f*w0.y; v[2] += f*w0.z; v[3] += f*w0.w;
    v[4] += f*w1.x; v[5] += f*w1.y; v[6] += f*w1.z; v[7] += f*w1.w;
    v[8] += f*w2.x; v[9] += f*w2.y; v[10]+= f*w2.z; v[11]+= f*w2.w;
  }
  float sum = 0.f, sq = 0.f;
  #pragma unroll
  for (int j = 0; j < 12; ++j) { sum += v[j]; sq += v[j]*v[j]; }
  #pragma unroll
  for (int o = 32; o > 0; o >>= 1) { sum += __shfl_xor(sum, o); sq += __shfl_xor(sq, o); }
  float mu = sum * (1.0f / D_);
  float rstd = rsqrtf(sq * (1.0f / D_) - mu * mu + 1e-6f);
  bf16x8 o8; bf16x4 o4;
  #pragma unroll
  for (int j = 0; j < 8; ++j) o8[j] = (bf16_t)gelu_exact((v[j] - mu) * rstd);
  #pragma unroll
  for (int j = 0; j < 4; ++j) o4[j] = (bf16_t)gelu_exact((v[8 + j] - mu) * rstd);
  size_t base = (size_t)m * D_;
  *(bf16x8*)(act1 + base + d8) = o8;
  *(bf16x4*)(act1 + base + d4) = o4;
}

// -------- LN(1e-5, g2, beta2) + gelu on bf16 rows -> bf16; wave per row --
__global__ __launch_bounds__(256) void ln2_kernel(
    const bf16_t* __restrict__ h2pre, const float* __restrict__ g2,
    const float* __restrict__ beta2, bf16_t* __restrict__ act2) {
  int wid = threadIdx.x >> 6, lane = threadIdx.x & 63;
  int m = blockIdx.x * 4 + wid;
  int d8 = lane * 8, d4 = 512 + lane * 4;
  size_t base = (size_t)m * D_;
  bf16x8 i8 = *(const bf16x8*)(h2pre + base + d8);
  bf16x4 i4 = *(const bf16x4*)(h2pre + base + d4);
  float v[12];
  #pragma unroll
  for (int j = 0; j < 8; ++j) v[j] = (float)i8[j];
  #pragma unroll
  for (int j = 0; j < 4; ++j) v[8 + j] = (float)i4[j];
  float sum = 0.f, sq = 0.f;
  #pragma unroll
  for (int j = 0; j < 12; ++j) { sum += v[j]; sq += v[j]*v[j]; }
  #pragma unroll
  for (int o = 32; o > 0; o >>= 1) { sum += __shfl_xor(sum, o); sq += __shfl_xor(sq, o); }
  float mu = sum * (1.0f / D_);
  float rstd = rsqrtf(sq * (1.0f / D_) - mu * mu + 1e-5f);
  float4 ga = *(const float4*)(g2 + d8);
  float4 gb = *(const float4*)(g2 + d8 + 4);
  float4 gc = *(const float4*)(g2 + d4);
  float4 ba = *(const float4*)(beta2 + d8);
  float4 bb = *(const float4*)(beta2 + d8 + 4);
  float4 bc = *(const float4*)(beta2 + d4);
  float g[12] = {ga.x,ga.y,ga.z,ga.w, gb.x,gb.y,gb.z,gb.w, gc.x,gc.y,gc.z,gc.w};
  float be[12]= {ba.x,ba.y,ba.z,ba.w, bb.x,bb.y,bb.z,bb.w, bc.x,bc.y,bc.z,bc.w};
  bf16x8 o8; bf16x4 o4;
  #pragma unroll
  for (int j = 0; j < 8; ++j) o8[j] = (bf16_t)gelu_exact((v[j] - mu) * rstd * g[j] + be[j]);
  #pragma unroll
  for (int j = 0; j < 4; ++j) o4[j] = (bf16_t)gelu_exact((v[8+j] - mu) * rstd * g[8+j] + be[8+j]);
  *(bf16x8*)(act2 + base + d8) = o8;
  *(bf16x4*)(act2 + base + d4) = o4;
}

// -------- segment max over bf16 h -> bf16 y; 4 waves split the t-range --
__global__ __launch_bounds__(256) void segmax_kernel(
    const bf16_t* __restrict__ h, const int* __restrict__ off,
    bf16_t* __restrict__ y) {
  int bp = blockIdx.x;
  int b = bp >> 9, p = bp & (P_ - 1);
  int t0 = off[p], t1 = off[p + 1];
  int wid = threadIdx.x >> 6, lane = threadIdx.x & 63;
  int d8 = lane * 8, d4 = 512 + lane * 4;
  const bf16_t* hb = h + (size_t)b * T_ * D_;
  float mx[12];
  #pragma unroll
  for (int j = 0; j < 12; ++j) mx[j] = -INFINITY;
  for (int t = t0 + wid; t < t1; t += 4) {
    const bf16_t* row = hb + (size_t)t * D_;
    bf16x8 a = *(const bf16x8*)(row + d8);
    bf16x4 c = *(const bf16x4*)(row + d4);
    #pragma unroll
    for (int j = 0; j < 8; ++j) mx[j] = fmaxf(mx[j], (float)a[j]);
    #pragma unroll
    for (int j = 0; j < 4; ++j) mx[8 + j] = fmaxf(mx[8 + j], (float)c[j]);
  }
  __shared__ float pm[4][D_];
  #pragma unroll
  for (int j = 0; j < 8; ++j) pm[wid][d8 + j] = mx[j];
  #pragma unroll
  for (int j = 0; j < 4; ++j) pm[wid][d4 + j] = mx[8 + j];
  __syncthreads();
  if (wid == 0) {
    bf16x8 o8; bf16x4 o4;
    #pragma unroll
    for (int j = 0; j < 8; ++j) {
      int d = d8 + j;
      o8[j] = (bf16_t)fmaxf(fmaxf(pm[0][d], pm[1][d]), fmaxf(pm[2][d], pm[3][d]));
    }
    #pragma unroll
    for (int j = 0; j < 4; ++j) {
      int d = d4 + j;
      o4[j] = (bf16_t)fmaxf(fmaxf(pm[0][d], pm[1][d]), fmaxf(pm[2][d], pm[3][d]));
    }
    *(bf16x8*)(y + (size_t)bp * D_ + d8) = o8;
    *(bf16x4*)(y + (size_t)bp * D_ + d4) = o4;
  }
}

// -------- final: segmax(raw fp32) + pos_embed -> out fp32 ---------------
__global__ __launch_bounds__(256) void final_kernel(
    const float* __restrict__ raw, const int* __restrict__ off,
    const float* __restrict__ pe, float* __restrict__ out) {
  int bp = blockIdx.x;
  int b = bp >> 9, p = bp & (P_ - 1);
  int t0 = off[p], t1 = off[p + 1];
  int wid = threadIdx.x >> 6, lane = threadIdx.x & 63;
  int d8 = lane * 8, d4 = 512 + lane * 4;
  const float* rb = raw + (size_t)b * T_ * D_;
  float mx[12];
  #pragma unroll
  for (int j = 0; j < 12; ++j) mx[j] = -INFINITY;
  for (int t = t0 + wid; t < t1; t += 4) {
    const float* row = rb + (size_t)t * D_;
    float4 r0 = *(const float4*)(row + d8);
    float4 r1 = *(const float4*)(row + d8 + 4);
    float4 r2 = *(const float4*)(row + d4);
    mx[0]=fmaxf(mx[0],r0.x); mx[1]=fmaxf(mx[1],r0.y); mx[2]=fmaxf(mx[2],r0.z); mx[3]=fmaxf(mx[3],r0.w);
    mx[4]=fmaxf(mx[4],r1.x); mx[5]=fmaxf(mx[5],r1.y); mx[6]=fmaxf(mx[6],r1.z); mx[7]=fmaxf(mx[7],r1.w);
    mx[8]=fmaxf(mx[8],r2.x); mx[9]=fmaxf(mx[9],r2.y); mx[10]=fmaxf(mx[10],r2.z); mx[11]=fmaxf(mx[11],r2.w);
  }
  __shared__ float pm[4][D_];
  #pragma unroll
  for (int j = 0; j < 8; ++j) pm[wid][d8 + j] = mx[j];
  #pragma unroll
  for (int j = 0; j < 4; ++j) pm[wid][d4 + j] = mx[8 + j];
  __syncthreads();
  if (wid == 0) {
    const float* per = pe + (size_t)p * D_;
    float* orow = out + (size_t)bp * D_;
    float4 o0, o1, o2;
    float r[12];
    #pragma unroll
    for (int j = 0; j < 8; ++j) {
      int d = d8 + j;
      r[j] = fmaxf(fmaxf(pm[0][d], pm[1][d]), fmaxf(pm[2][d], pm[3][d])) + per[d];
    }
    #pragma unroll
    for (int j = 0; j < 4; ++j) {
      int d = d4 + j;
      r[8 + j] = fmaxf(fmaxf(pm[0][d], pm[1][d]), fmaxf(pm[2][d], pm[3][d])) + per[d];
    }
    o0.x=r[0]; o0.y=r[1]; o0.z=r[2]; o0.w=r[3];
    o1.x=r[4]; o1.y=r[5]; o1.z=r[6]; o1.w=r[7];
    o2.x=r[8]; o2.y=r[9]; o2.z=r[10]; o2.w=r[11];
    *(float4*)(orow + d8) = o0;
    *(float4*)(orow + d8 + 4) = o1;
    *(float4*)(orow + d4) = o2;
  }
}

// -------- bf16 MFMA GEMM: C[M,N] = A[M,K] * BT[N,K]^T + addend ----------
// MODE 0: addend = bias[n].  MODE 2: addend = z[(b*512+seg[m]), n] (fp32).
// XCD-grouped work swizzle: all column-works of one m-row on one XCD.
template <int MODE, typename OutT>
__global__ __launch_bounds__(256) void gemm_kernel(
    const bf16_t* __restrict__ A, const bf16_t* __restrict__ BT,
    const float* __restrict__ addend, OutT* __restrict__ C,
    int M, int N, int K, const int* __restrict__ seg) {
  __shared__ bf16_t As[128 * 32];
  __shared__ bf16_t Bs[128 * 32];
  __shared__ int segm[128];
  int tid = threadIdx.x;
  int wave = tid >> 6, lane = tid & 63;
  int lr = lane & 15, hi = lane >> 4;
  int wm = wave >> 1, wn = wave & 1;

  // work swizzle: nb % 8 == 0 always here
  int nb = gridDim.x * gridDim.y;
  int bid = blockIdx.y * gridDim.x + blockIdx.x;
  int per = nb >> 3;
  int w = (bid & 7) * per + (bid >> 3);
  int wx = w % gridDim.x, wy = w / gridDim.x;
  int n0 = wx * 128, m0 = wy * 128;

  if (MODE == 2) {
    if (tid < 128) segm[tid] = seg[(m0 + tid) & (T_ - 1)];
  }

  f32x4 acc[4][4] = {};

  for (int kt = 0; kt < K; kt += 32) {
    __syncthreads();   // previous compute done (and segm visible on 1st iter)
    #pragma unroll
    for (int q = 0; q < 2; ++q) {
      int c = q * 256 + tid;
      int row = c >> 2, ko = (c & 3) * 8;
      gload16(A + (size_t)(m0 + row) * K + (kt + ko), (char*)As + q * 4096 + wave * 1024);
      gload16(BT + (size_t)(n0 + row) * K + (kt + ko), (char*)Bs + q * 4096 + wave * 1024);
    }
    __syncthreads();   // drains vmcnt before barrier

    bf16x8 af[4], bfr[4];
    #pragma unroll
    for (int i = 0; i < 4; ++i)
      af[i] = *reinterpret_cast<const bf16x8*>(&As[(size_t)(wm * 64 + i * 16 + lr) * 32 + hi * 8]);
    #pragma unroll
    for (int j = 0; j < 4; ++j)
      bfr[j] = *reinterpret_cast<const bf16x8*>(&Bs[(size_t)(wn * 64 + j * 16 + lr) * 32 + hi * 8]);
    #pragma unroll
    for (int i = 0; i < 4; ++i)
      #pragma unroll
      for (int j = 0; j < 4; ++j)
        acc[i][j] = __builtin_amdgcn_mfma_f32_16x16x32_bf16(af[i], bfr[j], acc[i][j], 0, 0, 0);
  }

  int zbase = (m0 >> 15) << 9;   // b * 512 (MODE 2)
  #pragma unroll
  for (int j = 0; j < 4; ++j) {
    int n = n0 + wn * 64 + j * 16 + lr;
    float bv = (MODE == 0) ? addend[n] : 0.f;
    #pragma unroll
    for (int i = 0; i < 4; ++i) {
      #pragma unroll
      for (int r = 0; r < 4; ++r) {
        int row = wm * 64 + i * 16 + hi * 4 + r;
        float add = bv;
        if (MODE == 2) add = addend[(size_t)(zbase + segm[row]) * D_ + n];
        C[(size_t)(m0 + row) * N + n] = (OutT)(acc[i][j][r] + add);
      }
    }
  }
}

extern "C" void kernel_launch(void* const* d_in, const int* in_sizes, int n_in,
                              void* d_out, int out_size, void* d_ws, size_t ws_size,
                              hipStream_t stream) {
  const float* latent       = (const float*)d_in[0];
  const int*   patch_index  = (const int*)d_in[1];
  const int*   patch_offset = (const int*)d_in[2];
  const float* pos_embed    = (const float*)d_in[3];
  const float* w1a  = (const float*)d_in[4];
  const float* b1a  = (const float*)d_in[5];
  const float* w1b  = (const float*)d_in[6];
  const float* b1b  = (const float*)d_in[7];
  const float* w2a  = (const float*)d_in[8];
  const float* b2a  = (const float*)d_in[9];
  const float* g2   = (const float*)d_in[10];
  const float* beta2= (const float*)d_in[11];
  const float* w2b  = (const float*)d_in[12];
  const float* b2b  = (const float*)d_in[13];

  float* out_f   = (float*)d_out;
  float* raw_out = out_f + (size_t)B_ * P_ * D_;

  char* ws = (char*)d_ws;
  size_t off = 0;
  auto take = [&](size_t bytes) {
    off = (off + 255) & ~(size_t)255;
    char* p = ws + off;
    off += bytes;
    return p;
  };
  int*    seg   = (int*)   take((size_t)T_ * 4);
  bf16_t* w1bT  = (bf16_t*)take((size_t)D_ * D_ * 2);
  bf16_t* w2aTT = (bf16_t*)take((size_t)D_ * D_ * 2);   // top half, transposed
  bf16_t* w2aBT = (bf16_t*)take((size_t)D_ * D_ * 2);   // bottom half, transposed
  bf16_t* w2bT  = (bf16_t*)take((size_t)D_ * D_ * 2);
  bf16_t* ybuf  = (bf16_t*)take((size_t)B_ * P_ * D_ * 2);
  float*  zbuf  = (float*) take((size_t)B_ * P_ * D_ * 4);
  bf16_t* bufY  = (bf16_t*)take((size_t)M_ * D_ * 2);
  size_t needX = (size_t)M_ * D_ * 2;
  size_t offX  = (off + 255) & ~(size_t)255;
  bf16_t* bufX;
  if (offX + needX <= ws_size) {
    bufX = (bf16_t*)take(needX);
  } else {
    // fallback: stash act1/h2pre in d_out's raw_latent region (dead before
    // GEMM3 overwrites it with the real fp32 raw_latent).
    bufX = (bf16_t*)raw_out;
  }

  seg_kernel<<<(T_ + 255) / 256, 256, 0, stream>>>(patch_offset, seg);
  dim3 wcb(32, 8);
  wconvT_kernel<<<dim3(D_/32, D_/32), wcb, 0, stream>>>(w1b, w1bT, D_, D_);
  wconvT_kernel<<<dim3(D_/32, D_/32), wcb, 0, stream>>>(w2a, w2aTT, D_, D_);
  wconvT_kernel<<<dim3(D_/32, D_/32), wcb, 0, stream>>>(w2a + (size_t)D_*D_, w2aBT, D_, D_);
  wconvT_kernel<<<dim3(D_/32, D_/32), wcb, 0, stream>>>(w2b, w2bT, D_, D_);

  // act1 = gelu(LN(latent[pidx] @ w1a + b1a))
  embed_kernel<<<M_ / 4, 256, 0, stream>>>((const float4*)latent, patch_index, w1a, b1a, bufX);

  // h = act1 @ w1b + b1b
  gemm_kernel<0, bf16_t><<<dim3(D_/128, M_/128), 256, 0, stream>>>(
      bufX, w1bT, b1b, bufY, M_, D_, D_, nullptr);

  // y = segmax(h)
  segmax_kernel<<<B_ * P_, 256, 0, stream>>>(bufY, patch_offset, ybuf);

  // z = y @ w2a_top + b2a   (1024 x 768 x 768, fp32 out)
  gemm_kernel<0, float><<<dim3(D_/128, (B_*P_)/128), 256, 0, stream>>>(
      ybuf, w2aTT, b2a, zbuf, B_*P_, D_, D_, nullptr);

  // h2pre = h @ w2a_bot + z[seg gather]
  gemm_kernel<2, bf16_t><<<dim3(D_/128, M_/128), 256, 0, stream>>>(
      bufY, w2aBT, zbuf, bufX, M_, D_, D_, seg);

  // act2 = gelu(LN(h2pre) * g2 + beta2)
  ln2_kernel<<<M_ / 4, 256, 0, stream>>>(bufX, g2, beta2, bufY);

  // raw = act2 @ w2b + b2b  (fp32, straight into d_out)
  gemm_kernel<0, float><<<dim3(D_/128, M_/128), 256, 0, stream>>>(
      bufY, w2bT, b2b, raw_out, M_, D_, D_, nullptr);

  // out = segmax(raw) + pos_embed
  final_kernel<<<B_ * P_, 256, 0, stream>>>(raw_out, patch_offset, pos_embed, out_f);
}

// Round 3
// 535.457 us; speedup vs baseline: 1.6600x; 1.0683x over previous
//
#include <hip/hip_runtime.h>
#include <hip/hip_bf16.h>
#include <math.h>

#define B_    2
#define NPTS_ 32768
#define T_    32768
#define P_    512
#define C_    4
#define D_    768
#define M_    (B_ * T_)   // 65536

typedef __bf16 bf16_t;
typedef __bf16 bf16x8 __attribute__((ext_vector_type(8)));
typedef __bf16 bf16x4 __attribute__((ext_vector_type(4)));
typedef float  f32x4  __attribute__((ext_vector_type(4)));

__device__ inline void gload16(const void* g, void* l) {
  __builtin_amdgcn_global_load_lds(
      (const __attribute__((address_space(1))) void*)g,
      (__attribute__((address_space(3))) void*)l, 16, 0, 0);
}

__device__ inline float gelu_exact(float x) {
  return 0.5f * x * (1.0f + erff(x * 0.70710678118654752f));
}

// order-preserving float <-> uint map (for atomicMax on floats)
__device__ inline unsigned fmap(float x) {
  unsigned u = __float_as_uint(x);
  return (u & 0x80000000u) ? ~u : (u | 0x80000000u);
}
__device__ inline float funmap(unsigned u) {
  unsigned v = (u & 0x80000000u) ? (u & 0x7FFFFFFFu) : ~u;
  return __uint_as_float(v);
}

// ---------------- seg[t] = segment id via binary search ----------------
__global__ void seg_kernel(const int* __restrict__ off, int* __restrict__ seg) {
  int t = blockIdx.x * blockDim.x + threadIdx.x;
  if (t >= T_) return;
  int lo = 0, hi = P_;
  while (lo < hi) {
    int mid = (lo + hi) >> 1;
    if (off[mid + 1] <= t) lo = mid + 1; else hi = mid;
  }
  seg[t] = lo;
}

// ---------------- zero the two uint-max buffers (adjacent) --------------
__global__ __launch_bounds__(256) void init_umax_kernel(uint4* __restrict__ u) {
  u[blockIdx.x * 256 + threadIdx.x] = make_uint4(0, 0, 0, 0);
}

// ---------------- unmap ymax -> bf16 y ---------------------------------
__global__ __launch_bounds__(256) void yconv_kernel(
    const uint4* __restrict__ ymax, bf16_t* __restrict__ y) {
  int t = blockIdx.x * 256 + threadIdx.x;   // 196608 total
  uint4 u = ymax[t];
  bf16x4 o;
  o[0] = (bf16_t)funmap(u.x); o[1] = (bf16_t)funmap(u.y);
  o[2] = (bf16_t)funmap(u.z); o[3] = (bf16_t)funmap(u.w);
  *(bf16x4*)(y + (size_t)t * 4) = o;
}

// ---------------- unmap rmax + pos_embed -> out fp32 -------------------
__global__ __launch_bounds__(256) void final2_kernel(
    const uint4* __restrict__ rmax, const float4* __restrict__ pe,
    float4* __restrict__ out) {
  int t = blockIdx.x * 256 + threadIdx.x;   // 196608 total
  int row = t / 192, col = t % 192;         // 768/4 = 192
  uint4 u = rmax[t];
  float4 p = pe[(row & (P_ - 1)) * 192 + col];
  float4 o;
  o.x = funmap(u.x) + p.x; o.y = funmap(u.y) + p.y;
  o.z = funmap(u.z) + p.z; o.w = funmap(u.w) + p.w;
  out[t] = o;
}

// ---- weight transpose fp32 [K][N] -> bf16 [N][K], LDS-tiled coalesced ----
__global__ __launch_bounds__(256) void wconvT_kernel(
    const float* __restrict__ src, bf16_t* __restrict__ dst, int K, int N) {
  __shared__ float tile[32][33];
  int n0 = blockIdx.x * 32, k0 = blockIdx.y * 32;
  int tx = threadIdx.x, ty = threadIdx.y;   // 32 x 8
  #pragma unroll
  for (int i = 0; i < 4; ++i)
    tile[ty + 8 * i][tx] = src[(size_t)(k0 + ty + 8 * i) * N + n0 + tx];
  __syncthreads();
  #pragma unroll
  for (int i = 0; i < 4; ++i)
    dst[(size_t)(n0 + ty + 8 * i) * K + k0 + tx] = (bf16_t)tile[tx][ty + 8 * i];
}

// -------- fused: gather latent -> @w1a + b1a -> LN(1e-6) -> gelu -> bf16
__global__ __launch_bounds__(256) void embed_kernel(
    const float4* __restrict__ latent4, const int* __restrict__ pidx,
    const float* __restrict__ w1a, const float* __restrict__ b1a,
    bf16_t* __restrict__ act1) {
  int wid = threadIdx.x >> 6, lane = threadIdx.x & 63;
  int m = blockIdx.x * 4 + wid;
  int b = m >> 15, t = m & (T_ - 1);
  float4 x = latent4[(size_t)b * NPTS_ + pidx[t]];
  int d8 = lane * 8, d4 = 512 + lane * 4;
  float v[12];
  {
    float4 a0 = *(const float4*)(b1a + d8);
    float4 a1 = *(const float4*)(b1a + d8 + 4);
    float4 a2 = *(const float4*)(b1a + d4);
    v[0]=a0.x; v[1]=a0.y; v[2]=a0.z; v[3]=a0.w;
    v[4]=a1.x; v[5]=a1.y; v[6]=a1.z; v[7]=a1.w;
    v[8]=a2.x; v[9]=a2.y; v[10]=a2.z; v[11]=a2.w;
  }
  float xk[4] = {x.x, x.y, x.z, x.w};
  #pragma unroll
  for (int k = 0; k < 4; ++k) {
    const float* w = w1a + k * D_;
    float4 w0 = *(const float4*)(w + d8);
    float4 w1 = *(const float4*)(w + d8 + 4);
    float4 w2 = *(const float4*)(w + d4);
    float f = xk[k];
    v[0] += f*w0.x; v[1] += f*w0.y; v[2] += f*w0.z; v[3] += f*w0.w;
    v[4] += f*w1.x; v[5] += f*w1.y; v[6] += f*w1.z; v[7] += f*w1.w;
    v[8] += f*w2.x; v[9] += f*w2.y; v[10]+= f*w2.z; v[11]+= f*w2.w;
  }
  float sum = 0.f, sq = 0.f;
  #pragma unroll
  for (int j = 0; j < 12; ++j) { sum += v[j]; sq += v[j]*v[j]; }
  #pragma unroll
  for (int o = 32; o > 0; o >>= 1) { sum += __shfl_xor(sum, o); sq += __shfl_xor(sq, o); }
  float mu = sum * (1.0f / D_);
  float rstd = rsqrtf(sq * (1.0f / D_) - mu * mu + 1e-6f);
  bf16x8 o8; bf16x4 o4;
  #pragma unroll
  for (int j = 0; j < 8; ++j) o8[j] = (bf16_t)gelu_exact((v[j] - mu) * rstd);
  #pragma unroll
  for (int j = 0; j < 4; ++j) o4[j] = (bf16_t)gelu_exact((v[8 + j] - mu) * rstd);
  size_t base = (size_t)m * D_;
  *(bf16x8*)(act1 + base + d8) = o8;
  *(bf16x4*)(act1 + base + d4) = o4;
}

// ---- h2 = h2partial + z[seg]; LN(1e-5, g2, beta2) + gelu -> bf16 -------
__global__ __launch_bounds__(256) void ln2_kernel(
    const bf16_t* __restrict__ h2pre, const float* __restrict__ z,
    const int* __restrict__ seg, const float* __restrict__ g2,
    const float* __restrict__ beta2, bf16_t* __restrict__ act2) {
  int wid = threadIdx.x >> 6, lane = threadIdx.x & 63;
  int m = blockIdx.x * 4 + wid;
  int b = m >> 15, t = m & (T_ - 1);
  int d8 = lane * 8, d4 = 512 + lane * 4;
  size_t base = (size_t)m * D_;
  const float* zrow = z + (size_t)((b << 9) + seg[t]) * D_;
  bf16x8 i8 = *(const bf16x8*)(h2pre + base + d8);
  bf16x4 i4 = *(const bf16x4*)(h2pre + base + d4);
  float4 z0 = *(const float4*)(zrow + d8);
  float4 z1 = *(const float4*)(zrow + d8 + 4);
  float4 z2 = *(const float4*)(zrow + d4);
  float v[12];
  #pragma unroll
  for (int j = 0; j < 8; ++j) v[j] = (float)i8[j];
  #pragma unroll
  for (int j = 0; j < 4; ++j) v[8 + j] = (float)i4[j];
  v[0]+=z0.x; v[1]+=z0.y; v[2]+=z0.z; v[3]+=z0.w;
  v[4]+=z1.x; v[5]+=z1.y; v[6]+=z1.z; v[7]+=z1.w;
  v[8]+=z2.x; v[9]+=z2.y; v[10]+=z2.z; v[11]+=z2.w;
  float sum = 0.f, sq = 0.f;
  #pragma unroll
  for (int j = 0; j < 12; ++j) { sum += v[j]; sq += v[j]*v[j]; }
  #pragma unroll
  for (int o = 32; o > 0; o >>= 1) { sum += __shfl_xor(sum, o); sq += __shfl_xor(sq, o); }
  float mu = sum * (1.0f / D_);
  float rstd = rsqrtf(sq * (1.0f / D_) - mu * mu + 1e-5f);
  float4 ga = *(const float4*)(g2 + d8);
  float4 gb = *(const float4*)(g2 + d8 + 4);
  float4 gc = *(const float4*)(g2 + d4);
  float4 ba = *(const float4*)(beta2 + d8);
  float4 bb = *(const float4*)(beta2 + d8 + 4);
  float4 bc = *(const float4*)(beta2 + d4);
  float g[12] = {ga.x,ga.y,ga.z,ga.w, gb.x,gb.y,gb.z,gb.w, gc.x,gc.y,gc.z,gc.w};
  float be[12]= {ba.x,ba.y,ba.z,ba.w, bb.x,bb.y,bb.z,bb.w, bc.x,bc.y,bc.z,bc.w};
  bf16x8 o8; bf16x4 o4;
  #pragma unroll
  for (int j = 0; j < 8; ++j) o8[j] = (bf16_t)gelu_exact((v[j] - mu) * rstd * g[j] + be[j]);
  #pragma unroll
  for (int j = 0; j < 4; ++j) o4[j] = (bf16_t)gelu_exact((v[8+j] - mu) * rstd * g[8+j] + be[8+j]);
  *(bf16x8*)(act2 + base + d8) = o8;
  *(bf16x4*)(act2 + base + d4) = o4;
}

// -------- bf16 MFMA GEMM: C[M,N] = A[M,K] * BT[N,K]^T + bias ------------
// MODE 0: addend = bias[n]. MODE 1: no addend.
// SEGMAX: additionally reduce fp32 results per (segment, n) into gmax via
//   LDS atomicMax (order-preserving uint map) + one global atomicMax each.
template <int MODE, bool SEGMAX, typename OutT>
__global__ __launch_bounds__(256) void gemm_kernel(
    const bf16_t* __restrict__ A, const bf16_t* __restrict__ BT,
    const float* __restrict__ addend, OutT* __restrict__ C,
    int M, int N, int K, const int* __restrict__ seg,
    unsigned* __restrict__ gmax) {
  __shared__ bf16_t As[128 * 32];
  __shared__ bf16_t Bs[128 * 32];
  __shared__ int segm[128];
  int tid = threadIdx.x;
  int wave = tid >> 6, lane = tid & 63;
  int lr = lane & 15, hi = lane >> 4;
  int wm = wave >> 1, wn = wave & 1;

  // XCD work swizzle (nb % 8 == 0 for all our grids)
  int nb = gridDim.x * gridDim.y;
  int bid = blockIdx.y * gridDim.x + blockIdx.x;
  int per = nb >> 3;
  int w = (bid & 7) * per + (bid >> 3);
  int wx = w % gridDim.x, wy = w / gridDim.x;
  int n0 = wx * 128, m0 = wy * 128;

  if (SEGMAX) {
    if (tid < 128) segm[tid] = seg[(m0 + tid) & (T_ - 1)];
  }

  f32x4 acc[4][4] = {};

  for (int kt = 0; kt < K; kt += 32) {
    __syncthreads();   // previous compute done (and segm visible on 1st iter)
    #pragma unroll
    for (int q = 0; q < 2; ++q) {
      int c = q * 256 + tid;
      int row = c >> 2, ko = (c & 3) * 8;
      gload16(A + (size_t)(m0 + row) * K + (kt + ko), (char*)As + q * 4096 + wave * 1024);
      gload16(BT + (size_t)(n0 + row) * K + (kt + ko), (char*)Bs + q * 4096 + wave * 1024);
    }
    __syncthreads();   // drains vmcnt before barrier

    bf16x8 af[4], bfr[4];
    #pragma unroll
    for (int i = 0; i < 4; ++i)
      af[i] = *reinterpret_cast<const bf16x8*>(&As[(size_t)(wm * 64 + i * 16 + lr) * 32 + hi * 8]);
    #pragma unroll
    for (int j = 0; j < 4; ++j)
      bfr[j] = *reinterpret_cast<const bf16x8*>(&Bs[(size_t)(wn * 64 + j * 16 + lr) * 32 + hi * 8]);
    #pragma unroll
    for (int i = 0; i < 4; ++i)
      #pragma unroll
      for (int j = 0; j < 4; ++j)
        acc[i][j] = __builtin_amdgcn_mfma_f32_16x16x32_bf16(af[i], bfr[j], acc[i][j], 0, 0, 0);
  }

  unsigned* smax = reinterpret_cast<unsigned*>(As);
  int sb = 0, zb = 0;
  if (SEGMAX) {
    __syncthreads();                 // all waves done reading As
    for (int q = tid; q < 8 * 128; q += 256) smax[q] = 0u;
    sb = segm[0];
    zb = (m0 >> 15) << 9;            // b * 512
    __syncthreads();
  }

  #pragma unroll
  for (int j = 0; j < 4; ++j) {
    int nl = wn * 64 + j * 16 + lr;
    int n = n0 + nl;
    float bv = (MODE == 0) ? addend[n] : 0.f;
    #pragma unroll
    for (int i = 0; i < 4; ++i) {
      int rbase = wm * 64 + i * 16 + hi * 4;
      float vv[4];
      #pragma unroll
      for (int r = 0; r < 4; ++r) {
        vv[r] = acc[i][j][r] + bv;
        C[(size_t)(m0 + rbase + r) * N + n] = (OutT)vv[r];
      }
      if (SEGMAX) {
        int sA = segm[rbase] - sb, sB = segm[rbase + 3] - sb;
        if (sA == sB) {
          float mx = fmaxf(fmaxf(vv[0], vv[1]), fmaxf(vv[2], vv[3]));
          atomicMax(&smax[sA * 128 + nl], fmap(mx));
        } else {
          #pragma unroll
          for (int r = 0; r < 4; ++r)
            atomicMax(&smax[(segm[rbase + r] - sb) * 128 + nl], fmap(vv[r]));
        }
      }
    }
  }

  if (SEGMAX) {
    __syncthreads();
    int nseg = segm[127] - sb + 1;
    for (int q = tid; q < nseg * 128; q += 256) {
      int sl = q >> 7, nl2 = q & 127;
      atomicMax(&gmax[(size_t)(zb + sb + sl) * D_ + n0 + nl2], smax[q]);
    }
  }
}

extern "C" void kernel_launch(void* const* d_in, const int* in_sizes, int n_in,
                              void* d_out, int out_size, void* d_ws, size_t ws_size,
                              hipStream_t stream) {
  const float* latent       = (const float*)d_in[0];
  const int*   patch_index  = (const int*)d_in[1];
  const int*   patch_offset = (const int*)d_in[2];
  const float* pos_embed    = (const float*)d_in[3];
  const float* w1a  = (const float*)d_in[4];
  const float* b1a  = (const float*)d_in[5];
  const float* w1b  = (const float*)d_in[6];
  const float* b1b  = (const float*)d_in[7];
  const float* w2a  = (const float*)d_in[8];
  const float* b2a  = (const float*)d_in[9];
  const float* g2   = (const float*)d_in[10];
  const float* beta2= (const float*)d_in[11];
  const float* w2b  = (const float*)d_in[12];
  const float* b2b  = (const float*)d_in[13];

  float* out_f   = (float*)d_out;
  float* raw_out = out_f + (size_t)B_ * P_ * D_;

  char* ws = (char*)d_ws;
  size_t off = 0;
  auto take = [&](size_t bytes) {
    off = (off + 255) & ~(size_t)255;
    char* p = ws + off;
    off += bytes;
    return p;
  };
  int*      seg   = (int*)     take((size_t)T_ * 4);
  bf16_t*   w1bT  = (bf16_t*)  take((size_t)D_ * D_ * 2);
  bf16_t*   w2aTT = (bf16_t*)  take((size_t)D_ * D_ * 2);
  bf16_t*   w2aBT = (bf16_t*)  take((size_t)D_ * D_ * 2);
  bf16_t*   w2bT  = (bf16_t*)  take((size_t)D_ * D_ * 2);
  bf16_t*   ybuf  = (bf16_t*)  take((size_t)B_ * P_ * D_ * 2);
  float*    zbuf  = (float*)   take((size_t)B_ * P_ * D_ * 4);
  unsigned* umax  = (unsigned*)take((size_t)2 * B_ * P_ * D_ * 4);  // ymax|rmax
  unsigned* ymax  = umax;
  unsigned* rmax  = umax + (size_t)B_ * P_ * D_;
  bf16_t*   bufY  = (bf16_t*)  take((size_t)M_ * D_ * 2);
  size_t needX = (size_t)M_ * D_ * 2;
  size_t offX  = (off + 255) & ~(size_t)255;
  bf16_t* bufX;
  if (offX + needX <= ws_size) {
    bufX = (bf16_t*)take(needX);
  } else {
    bufX = (bf16_t*)raw_out;  // dead before gemm3 overwrites with real raw
  }

  seg_kernel<<<(T_ + 255) / 256, 256, 0, stream>>>(patch_offset, seg);
  init_umax_kernel<<<(2 * B_ * P_ * D_) / (4 * 256), 256, 0, stream>>>((uint4*)umax);
  dim3 wcb(32, 8);
  wconvT_kernel<<<dim3(D_/32, D_/32), wcb, 0, stream>>>(w1b, w1bT, D_, D_);
  wconvT_kernel<<<dim3(D_/32, D_/32), wcb, 0, stream>>>(w2a, w2aTT, D_, D_);
  wconvT_kernel<<<dim3(D_/32, D_/32), wcb, 0, stream>>>(w2a + (size_t)D_*D_, w2aBT, D_, D_);
  wconvT_kernel<<<dim3(D_/32, D_/32), wcb, 0, stream>>>(w2b, w2bT, D_, D_);

  // act1 = gelu(LN(latent[pidx] @ w1a + b1a))
  embed_kernel<<<M_ / 4, 256, 0, stream>>>((const float4*)latent, patch_index, w1a, b1a, bufX);

  // h = act1 @ w1b + b1b; fused y = segmax(h) -> ymax
  gemm_kernel<0, true, bf16_t><<<dim3(D_/128, M_/128), 256, 0, stream>>>(
      bufX, w1bT, b1b, bufY, M_, D_, D_, seg, ymax);

  // y bf16
  yconv_kernel<<<(B_ * P_ * D_) / (4 * 256), 256, 0, stream>>>((const uint4*)ymax, ybuf);

  // z = y @ w2a_top + b2a   (1024 x 768 x 768, fp32 out)
  gemm_kernel<0, false, float><<<dim3(D_/128, (B_*P_)/128), 256, 0, stream>>>(
      ybuf, w2aTT, b2a, zbuf, B_*P_, D_, D_, nullptr, nullptr);

  // h2partial = h @ w2a_bot   (no bias; z added in ln2)
  gemm_kernel<1, false, bf16_t><<<dim3(D_/128, M_/128), 256, 0, stream>>>(
      bufY, w2aBT, nullptr, bufX, M_, D_, D_, nullptr, nullptr);

  // act2 = gelu(LN(h2partial + z[seg]) * g2 + beta2)
  ln2_kernel<<<M_ / 4, 256, 0, stream>>>(bufX, zbuf, seg, g2, beta2, bufY);

  // raw = act2 @ w2b + b2b (fp32 -> d_out); fused segmax -> rmax
  gemm_kernel<0, true, float><<<dim3(D_/128, M_/128), 256, 0, stream>>>(
      bufY, w2bT, b2b, raw_out, M_, D_, D_, seg, rmax);

  // out = unmap(rmax) + pos_embed
  final2_kernel<<<(B_ * P_ * D_) / (4 * 256), 256, 0, stream>>>(
      (const uint4*)rmax, (const float4*)pos_embed, (float4*)out_f);
}

// Round 4
// 456.869 us; speedup vs baseline: 1.9456x; 1.1720x over previous
//
#include <hip/hip_runtime.h>
#include <hip/hip_bf16.h>
#include <math.h>

#define B_    2
#define NPTS_ 32768
#define T_    32768
#define P_    512
#define C_    4
#define D_    768
#define M_    (B_ * T_)   // 65536

typedef __bf16 bf16_t;
typedef __bf16 bf16x8 __attribute__((ext_vector_type(8)));
typedef __bf16 bf16x4 __attribute__((ext_vector_type(4)));
typedef float  f32x4  __attribute__((ext_vector_type(4)));

__device__ inline void gload16(const void* g, void* l) {
  __builtin_amdgcn_global_load_lds(
      (const __attribute__((address_space(1))) void*)g,
      (__attribute__((address_space(3))) void*)l, 16, 0, 0);
}

__device__ inline float gelu_exact(float x) {
  return 0.5f * x * (1.0f + erff(x * 0.70710678118654752f));
}

// order-preserving float <-> uint map (for atomicMax on floats)
__device__ inline unsigned fmap(float x) {
  unsigned u = __float_as_uint(x);
  return (u & 0x80000000u) ? ~u : (u | 0x80000000u);
}
__device__ inline float funmap(unsigned u) {
  unsigned v = (u & 0x80000000u) ? (u & 0x7FFFFFFFu) : ~u;
  return __uint_as_float(v);
}

// ---------------- seg[t] = segment id via binary search ----------------
__global__ void seg_kernel(const int* __restrict__ off, int* __restrict__ seg) {
  int t = blockIdx.x * blockDim.x + threadIdx.x;
  if (t >= T_) return;
  int lo = 0, hi = P_;
  while (lo < hi) {
    int mid = (lo + hi) >> 1;
    if (off[mid + 1] <= t) lo = mid + 1; else hi = mid;
  }
  seg[t] = lo;
}

// ---------------- zero the two uint-max buffers (adjacent) --------------
__global__ __launch_bounds__(256) void init_umax_kernel(uint4* __restrict__ u) {
  u[blockIdx.x * 256 + threadIdx.x] = make_uint4(0, 0, 0, 0);
}

// ---------------- unmap ymax -> bf16 y ---------------------------------
__global__ __launch_bounds__(256) void yconv_kernel(
    const uint4* __restrict__ ymax, bf16_t* __restrict__ y) {
  int t = blockIdx.x * 256 + threadIdx.x;   // 196608 total
  uint4 u = ymax[t];
  bf16x4 o;
  o[0] = (bf16_t)funmap(u.x); o[1] = (bf16_t)funmap(u.y);
  o[2] = (bf16_t)funmap(u.z); o[3] = (bf16_t)funmap(u.w);
  *(bf16x4*)(y + (size_t)t * 4) = o;
}

// ---------------- unmap rmax + pos_embed -> out fp32 -------------------
__global__ __launch_bounds__(256) void final2_kernel(
    const uint4* __restrict__ rmax, const float4* __restrict__ pe,
    float4* __restrict__ out) {
  int t = blockIdx.x * 256 + threadIdx.x;   // 196608 total
  int row = t / 192, col = t % 192;         // 768/4 = 192
  uint4 u = rmax[t];
  float4 p = pe[(row & (P_ - 1)) * 192 + col];
  float4 o;
  o.x = funmap(u.x) + p.x; o.y = funmap(u.y) + p.y;
  o.z = funmap(u.z) + p.z; o.w = funmap(u.w) + p.w;
  out[t] = o;
}

// ---- weight transpose fp32 [K][N] -> bf16 [N][K], LDS-tiled coalesced ----
__global__ __launch_bounds__(256) void wconvT_kernel(
    const float* __restrict__ src, bf16_t* __restrict__ dst, int K, int N) {
  __shared__ float tile[32][33];
  int n0 = blockIdx.x * 32, k0 = blockIdx.y * 32;
  int tx = threadIdx.x, ty = threadIdx.y;   // 32 x 8
  #pragma unroll
  for (int i = 0; i < 4; ++i)
    tile[ty + 8 * i][tx] = src[(size_t)(k0 + ty + 8 * i) * N + n0 + tx];
  __syncthreads();
  #pragma unroll
  for (int i = 0; i < 4; ++i)
    dst[(size_t)(n0 + ty + 8 * i) * K + k0 + tx] = (bf16_t)tile[tx][ty + 8 * i];
}

// -------- fused: gather latent -> @w1a + b1a -> LN(1e-6) -> gelu -> bf16
__global__ __launch_bounds__(256) void embed_kernel(
    const float4* __restrict__ latent4, const int* __restrict__ pidx,
    const float* __restrict__ w1a, const float* __restrict__ b1a,
    bf16_t* __restrict__ act1) {
  int wid = threadIdx.x >> 6, lane = threadIdx.x & 63;
  int m = blockIdx.x * 4 + wid;
  int b = m >> 15, t = m & (T_ - 1);
  float4 x = latent4[(size_t)b * NPTS_ + pidx[t]];
  int d8 = lane * 8, d4 = 512 + lane * 4;
  float v[12];
  {
    float4 a0 = *(const float4*)(b1a + d8);
    float4 a1 = *(const float4*)(b1a + d8 + 4);
    float4 a2 = *(const float4*)(b1a + d4);
    v[0]=a0.x; v[1]=a0.y; v[2]=a0.z; v[3]=a0.w;
    v[4]=a1.x; v[5]=a1.y; v[6]=a1.z; v[7]=a1.w;
    v[8]=a2.x; v[9]=a2.y; v[10]=a2.z; v[11]=a2.w;
  }
  float xk[4] = {x.x, x.y, x.z, x.w};
  #pragma unroll
  for (int k = 0; k < 4; ++k) {
    const float* w = w1a + k * D_;
    float4 w0 = *(const float4*)(w + d8);
    float4 w1 = *(const float4*)(w + d8 + 4);
    float4 w2 = *(const float4*)(w + d4);
    float f = xk[k];
    v[0] += f*w0.x; v[1] += f*w0.y; v[2] += f*w0.z; v[3] += f*w0.w;
    v[4] += f*w1.x; v[5] += f*w1.y; v[6] += f*w1.z; v[7] += f*w1.w;
    v[8] += f*w2.x; v[9] += f*w2.y; v[10]+= f*w2.z; v[11]+= f*w2.w;
  }
  float sum = 0.f, sq = 0.f;
  #pragma unroll
  for (int j = 0; j < 12; ++j) { sum += v[j]; sq += v[j]*v[j]; }
  #pragma unroll
  for (int o = 32; o > 0; o >>= 1) { sum += __shfl_xor(sum, o); sq += __shfl_xor(sq, o); }
  float mu = sum * (1.0f / D_);
  float rstd = rsqrtf(sq * (1.0f / D_) - mu * mu + 1e-6f);
  bf16x8 o8; bf16x4 o4;
  #pragma unroll
  for (int j = 0; j < 8; ++j) o8[j] = (bf16_t)gelu_exact((v[j] - mu) * rstd);
  #pragma unroll
  for (int j = 0; j < 4; ++j) o4[j] = (bf16_t)gelu_exact((v[8 + j] - mu) * rstd);
  size_t base = (size_t)m * D_;
  *(bf16x8*)(act1 + base + d8) = o8;
  *(bf16x4*)(act1 + base + d4) = o4;
}

// ---- h2 = h2partial + z[seg]; LN(1e-5, g2, beta2) + gelu -> bf16 -------
__global__ __launch_bounds__(256) void ln2_kernel(
    const bf16_t* __restrict__ h2pre, const float* __restrict__ z,
    const int* __restrict__ seg, const float* __restrict__ g2,
    const float* __restrict__ beta2, bf16_t* __restrict__ act2) {
  int wid = threadIdx.x >> 6, lane = threadIdx.x & 63;
  int m = blockIdx.x * 4 + wid;
  int b = m >> 15, t = m & (T_ - 1);
  int d8 = lane * 8, d4 = 512 + lane * 4;
  size_t base = (size_t)m * D_;
  const float* zrow = z + (size_t)((b << 9) + seg[t]) * D_;
  bf16x8 i8 = *(const bf16x8*)(h2pre + base + d8);
  bf16x4 i4 = *(const bf16x4*)(h2pre + base + d4);
  float4 z0 = *(const float4*)(zrow + d8);
  float4 z1 = *(const float4*)(zrow + d8 + 4);
  float4 z2 = *(const float4*)(zrow + d4);
  float v[12];
  #pragma unroll
  for (int j = 0; j < 8; ++j) v[j] = (float)i8[j];
  #pragma unroll
  for (int j = 0; j < 4; ++j) v[8 + j] = (float)i4[j];
  v[0]+=z0.x; v[1]+=z0.y; v[2]+=z0.z; v[3]+=z0.w;
  v[4]+=z1.x; v[5]+=z1.y; v[6]+=z1.z; v[7]+=z1.w;
  v[8]+=z2.x; v[9]+=z2.y; v[10]+=z2.z; v[11]+=z2.w;
  float sum = 0.f, sq = 0.f;
  #pragma unroll
  for (int j = 0; j < 12; ++j) { sum += v[j]; sq += v[j]*v[j]; }
  #pragma unroll
  for (int o = 32; o > 0; o >>= 1) { sum += __shfl_xor(sum, o); sq += __shfl_xor(sq, o); }
  float mu = sum * (1.0f / D_);
  float rstd = rsqrtf(sq * (1.0f / D_) - mu * mu + 1e-5f);
  float4 ga = *(const float4*)(g2 + d8);
  float4 gb = *(const float4*)(g2 + d8 + 4);
  float4 gc = *(const float4*)(g2 + d4);
  float4 ba = *(const float4*)(beta2 + d8);
  float4 bb = *(const float4*)(beta2 + d8 + 4);
  float4 bc = *(const float4*)(beta2 + d4);
  float g[12] = {ga.x,ga.y,ga.z,ga.w, gb.x,gb.y,gb.z,gb.w, gc.x,gc.y,gc.z,gc.w};
  float be[12]= {ba.x,ba.y,ba.z,ba.w, bb.x,bb.y,bb.z,bb.w, bc.x,bc.y,bc.z,bc.w};
  bf16x8 o8; bf16x4 o4;
  #pragma unroll
  for (int j = 0; j < 8; ++j) o8[j] = (bf16_t)gelu_exact((v[j] - mu) * rstd * g[j] + be[j]);
  #pragma unroll
  for (int j = 0; j < 4; ++j) o4[j] = (bf16_t)gelu_exact((v[8+j] - mu) * rstd * g[8+j] + be[8+j]);
  *(bf16x8*)(act2 + base + d8) = o8;
  *(bf16x4*)(act2 + base + d4) = o4;
}

// ===== 256x256 8-phase MFMA GEMM (T2+T3+T4+T5), K = N = 768 =============
// C[M,768] = A[M,768] * BT[768,768]^T (+bias) (+fused segment-max).
// 8 waves (2M x 4N), BK=64, double-buffered LDS (8 half-tile slots x 16KB).
// Stage schedule: A halves of K-tile j+2 at q2 of j, B halves at q3;
// one counted vmcnt(8) per K-tile at q0-top (never drains mid-loop).
// LDS swizzle: 16B-chunk index ^= (row&7), applied on pre-swizzled global
// source (linear gload_lds dest) and on ds_read address (involution).
#define STAGE_A(P2, KTG)                                                     \
  { _Pragma("unroll")                                                        \
    for (int h = 0; h < 2; ++h) {                                            \
      _Pragma("unroll")                                                      \
      for (int ps = 0; ps < 2; ++ps) {                                       \
        int c = ps * 512 + wid * 64 + lane;                                  \
        int rw = c >> 3;                                                     \
        int cs = (c & 7) ^ (rw & 7);                                         \
        gload16(A + (size_t)(m0 + h * 128 + rw) * 768 + (KTG) + cs * 8,      \
                lds + (P2) * 65536 + h * 16384 + ps * 8192 + wid * 1024);    \
      } } }

#define STAGE_B(P2, KTG)                                                     \
  { _Pragma("unroll")                                                        \
    for (int h = 0; h < 2; ++h) {                                            \
      _Pragma("unroll")                                                      \
      for (int ps = 0; ps < 2; ++ps) {                                       \
        int c = ps * 512 + wid * 64 + lane;                                  \
        int rw = c >> 3;                                                     \
        int cs = (c & 7) ^ (rw & 7);                                         \
        gload16(BT + (size_t)(n0 + h * 128 + rw) * 768 + (KTG) + cs * 8,     \
                lds + (P2) * 65536 + 32768 + h * 16384 + ps * 8192 + wid * 1024); \
      } } }

template <bool HASBIAS, bool SEGMAX, typename OutT>
__global__ __launch_bounds__(512, 1) void gemm256_kernel(
    const bf16_t* __restrict__ A, const bf16_t* __restrict__ BT,
    const float* __restrict__ bias, OutT* __restrict__ C,
    const int* __restrict__ seg, unsigned* __restrict__ gmax) {
  constexpr int NT = 12;                 // 768 / 64
  __shared__ __align__(16) char lds[131072];
  __shared__ int segm[256];
  int tid = threadIdx.x;
  int wid = tid >> 6, lane = tid & 63;
  int lr = lane & 15, hi = lane >> 4;
  int wm = wid >> 2, wn = wid & 3;

  int gx = gridDim.x;                    // 3
  int nb = gx * gridDim.y;
  int bid = blockIdx.y * gx + blockIdx.x;
  int w = ((nb & 7) == 0) ? ((bid & 7) * (nb >> 3) + (bid >> 3)) : bid;
  int bx = w % gx, by = w / gx;
  int n0 = bx * 256, m0 = by * 256;

  if (SEGMAX) { if (tid < 256) segm[tid] = seg[(m0 + tid) & (T_ - 1)]; }

  f32x4 acc[8][4] = {};
  bf16x8 af0[4][2], af1[4][2], bf0[2][2], bf1[2][2];
  int cx = lr & 7;

  // prologue: stage K-tiles 0 (parity 0) and 1 (parity 1); 16 loads/thread
  STAGE_A(0, 0); STAGE_B(0, 0);
  STAGE_A(1, 64); STAGE_B(1, 64);

  for (int j = 0; j < NT; ++j) {
    int p = j & 1;
    const char* base = lds + p * 65536;
    // ---- q0: vmcnt gate + ds_read(A mq0, B nq0) + MFMA(mq0,nq0) ----
    if (j < NT - 1) asm volatile("s_waitcnt vmcnt(8)" ::: "memory");
    else            asm volatile("s_waitcnt vmcnt(0)" ::: "memory");
    __builtin_amdgcn_s_barrier();
    #pragma unroll
    for (int i = 0; i < 4; ++i)
      #pragma unroll
      for (int s = 0; s < 2; ++s) {
        int row = i * 16 + lr;
        int ch = (s * 4 + hi) ^ cx;
        af0[i][s] = *(const bf16x8*)(base + wm * 16384 + row * 128 + ch * 16);
      }
    #pragma unroll
    for (int jb = 0; jb < 2; ++jb)
      #pragma unroll
      for (int s = 0; s < 2; ++s) {
        int nrow = wn * 64 + jb * 16 + lr;
        int ch = (s * 4 + hi) ^ cx;
        bf0[jb][s] = *(const bf16x8*)(base + 32768 + (nrow >> 7) * 16384 +
                                      (nrow & 127) * 128 + ch * 16);
      }
    __builtin_amdgcn_s_barrier();
    __builtin_amdgcn_s_setprio(1);
    #pragma unroll
    for (int i = 0; i < 4; ++i)
      #pragma unroll
      for (int jb = 0; jb < 2; ++jb)
        #pragma unroll
        for (int s = 0; s < 2; ++s)
          acc[i][jb] = __builtin_amdgcn_mfma_f32_16x16x32_bf16(af0[i][s], bf0[jb][s], acc[i][jb], 0, 0, 0);
    __builtin_amdgcn_s_setprio(0);
    __builtin_amdgcn_s_barrier();

    // ---- q1: ds_read(A mq1) + MFMA(mq1,nq0) ----
    #pragma unroll
    for (int i = 0; i < 4; ++i)
      #pragma unroll
      for (int s = 0; s < 2; ++s) {
        int row = 64 + i * 16 + lr;
        int ch = (s * 4 + hi) ^ cx;
        af1[i][s] = *(const bf16x8*)(base + wm * 16384 + row * 128 + ch * 16);
      }
    __builtin_amdgcn_s_barrier();
    __builtin_amdgcn_s_setprio(1);
    #pragma unroll
    for (int i = 0; i < 4; ++i)
      #pragma unroll
      for (int jb = 0; jb < 2; ++jb)
        #pragma unroll
        for (int s = 0; s < 2; ++s)
          acc[4 + i][jb] = __builtin_amdgcn_mfma_f32_16x16x32_bf16(af1[i][s], bf0[jb][s], acc[4 + i][jb], 0, 0, 0);
    __builtin_amdgcn_s_setprio(0);
    __builtin_amdgcn_s_barrier();

    // ---- q2: ds_read(B nq1) + stage A[j+2] + MFMA(mq0,nq1) ----
    #pragma unroll
    for (int jb = 0; jb < 2; ++jb)
      #pragma unroll
      for (int s = 0; s < 2; ++s) {
        int nrow = wn * 64 + 32 + jb * 16 + lr;
        int ch = (s * 4 + hi) ^ cx;
        bf1[jb][s] = *(const bf16x8*)(base + 32768 + (nrow >> 7) * 16384 +
                                      (nrow & 127) * 128 + ch * 16);
      }
    if (j + 2 < NT) STAGE_A(p, (j + 2) * 64);
    __builtin_amdgcn_s_barrier();
    __builtin_amdgcn_s_setprio(1);
    #pragma unroll
    for (int i = 0; i < 4; ++i)
      #pragma unroll
      for (int jb = 0; jb < 2; ++jb)
        #pragma unroll
        for (int s = 0; s < 2; ++s)
          acc[i][2 + jb] = __builtin_amdgcn_mfma_f32_16x16x32_bf16(af0[i][s], bf1[jb][s], acc[i][2 + jb], 0, 0, 0);
    __builtin_amdgcn_s_setprio(0);
    __builtin_amdgcn_s_barrier();

    // ---- q3: stage B[j+2] + MFMA(mq1,nq1) ----
    if (j + 2 < NT) STAGE_B(p, (j + 2) * 64);
    __builtin_amdgcn_s_barrier();
    __builtin_amdgcn_s_setprio(1);
    #pragma unroll
    for (int i = 0; i < 4; ++i)
      #pragma unroll
      for (int jb = 0; jb < 2; ++jb)
        #pragma unroll
        for (int s = 0; s < 2; ++s)
          acc[4 + i][2 + jb] = __builtin_amdgcn_mfma_f32_16x16x32_bf16(af1[i][s], bf1[jb][s], acc[4 + i][2 + jb], 0, 0, 0);
    __builtin_amdgcn_s_setprio(0);
    // q3 end barrier is next iteration's q0 barrier (or epilogue barrier)
  }

  // ---- epilogue: bias + C store + fused segmax ----
  unsigned* smax = reinterpret_cast<unsigned*>(lds);
  int sb = 0, zb = 0;
  if (SEGMAX) {
    __builtin_amdgcn_s_barrier();        // LDS tiles dead for all waves
    sb = segm[0];
    zb = (m0 >> 15) << 9;                // batch * 512
    for (int q = tid; q < 16 * 256; q += 512) smax[q] = 0u;
    __syncthreads();
  }

  #pragma unroll
  for (int jn = 0; jn < 4; ++jn) {
    int nl = wn * 64 + jn * 16 + lr;
    int n = n0 + nl;
    float bv = HASBIAS ? bias[n] : 0.f;
    #pragma unroll
    for (int i = 0; i < 8; ++i) {
      int rb = wm * 128 + i * 16 + hi * 4;
      float vv[4];
      #pragma unroll
      for (int r = 0; r < 4; ++r) {
        vv[r] = acc[i][jn][r] + bv;
        C[(size_t)(m0 + rb + r) * 768 + n] = (OutT)vv[r];
      }
      if (SEGMAX) {
        int sA = segm[rb] - sb, sB = segm[rb + 3] - sb;
        if (sA == sB) {
          float mx = fmaxf(fmaxf(vv[0], vv[1]), fmaxf(vv[2], vv[3]));
          atomicMax(&smax[sA * 256 + nl], fmap(mx));
        } else {
          #pragma unroll
          for (int r = 0; r < 4; ++r)
            atomicMax(&smax[(segm[rb + r] - sb) * 256 + nl], fmap(vv[r]));
        }
      }
    }
  }

  if (SEGMAX) {
    __syncthreads();
    int nseg = segm[255] - sb + 1;
    for (int q = tid; q < nseg * 256; q += 512) {
      int sl = q >> 8, nl2 = q & 255;
      atomicMax(&gmax[(size_t)(zb + sb + sl) * 768 + n0 + nl2], smax[q]);
    }
  }
}

extern "C" void kernel_launch(void* const* d_in, const int* in_sizes, int n_in,
                              void* d_out, int out_size, void* d_ws, size_t ws_size,
                              hipStream_t stream) {
  const float* latent       = (const float*)d_in[0];
  const int*   patch_index  = (const int*)d_in[1];
  const int*   patch_offset = (const int*)d_in[2];
  const float* pos_embed    = (const float*)d_in[3];
  const float* w1a  = (const float*)d_in[4];
  const float* b1a  = (const float*)d_in[5];
  const float* w1b  = (const float*)d_in[6];
  const float* b1b  = (const float*)d_in[7];
  const float* w2a  = (const float*)d_in[8];
  const float* b2a  = (const float*)d_in[9];
  const float* g2   = (const float*)d_in[10];
  const float* beta2= (const float*)d_in[11];
  const float* w2b  = (const float*)d_in[12];
  const float* b2b  = (const float*)d_in[13];

  float* out_f   = (float*)d_out;
  float* raw_out = out_f + (size_t)B_ * P_ * D_;

  char* ws = (char*)d_ws;
  size_t off = 0;
  auto take = [&](size_t bytes) {
    off = (off + 255) & ~(size_t)255;
    char* p = ws + off;
    off += bytes;
    return p;
  };
  int*      seg   = (int*)     take((size_t)T_ * 4);
  bf16_t*   w1bT  = (bf16_t*)  take((size_t)D_ * D_ * 2);
  bf16_t*   w2aTT = (bf16_t*)  take((size_t)D_ * D_ * 2);
  bf16_t*   w2aBT = (bf16_t*)  take((size_t)D_ * D_ * 2);
  bf16_t*   w2bT  = (bf16_t*)  take((size_t)D_ * D_ * 2);
  bf16_t*   ybuf  = (bf16_t*)  take((size_t)B_ * P_ * D_ * 2);
  float*    zbuf  = (float*)   take((size_t)B_ * P_ * D_ * 4);
  unsigned* umax  = (unsigned*)take((size_t)2 * B_ * P_ * D_ * 4);  // ymax|rmax
  unsigned* ymax  = umax;
  unsigned* rmax  = umax + (size_t)B_ * P_ * D_;
  bf16_t*   bufY  = (bf16_t*)  take((size_t)M_ * D_ * 2);
  size_t needX = (size_t)M_ * D_ * 2;
  size_t offX  = (off + 255) & ~(size_t)255;
  bf16_t* bufX;
  if (offX + needX <= ws_size) {
    bufX = (bf16_t*)take(needX);
  } else {
    bufX = (bf16_t*)raw_out;  // dead before gemm3 overwrites with real raw
  }

  seg_kernel<<<(T_ + 255) / 256, 256, 0, stream>>>(patch_offset, seg);
  init_umax_kernel<<<(2 * B_ * P_ * D_) / (4 * 256), 256, 0, stream>>>((uint4*)umax);
  dim3 wcb(32, 8);
  wconvT_kernel<<<dim3(D_/32, D_/32), wcb, 0, stream>>>(w1b, w1bT, D_, D_);
  wconvT_kernel<<<dim3(D_/32, D_/32), wcb, 0, stream>>>(w2a, w2aTT, D_, D_);
  wconvT_kernel<<<dim3(D_/32, D_/32), wcb, 0, stream>>>(w2a + (size_t)D_*D_, w2aBT, D_, D_);
  wconvT_kernel<<<dim3(D_/32, D_/32), wcb, 0, stream>>>(w2b, w2bT, D_, D_);

  // act1 = gelu(LN(latent[pidx] @ w1a + b1a))
  embed_kernel<<<M_ / 4, 256, 0, stream>>>((const float4*)latent, patch_index, w1a, b1a, bufX);

  // h = act1 @ w1b + b1b; fused y = segmax(h) -> ymax
  gemm256_kernel<true, true, bf16_t><<<dim3(3, M_/256), 512, 0, stream>>>(
      bufX, w1bT, b1b, bufY, seg, ymax);

  // y bf16
  yconv_kernel<<<(B_ * P_ * D_) / (4 * 256), 256, 0, stream>>>((const uint4*)ymax, ybuf);

  // z = y @ w2a_top + b2a   (1024 x 768 x 768, fp32 out)
  gemm256_kernel<true, false, float><<<dim3(3, (B_*P_)/256), 512, 0, stream>>>(
      ybuf, w2aTT, b2a, zbuf, nullptr, nullptr);

  // h2partial = h @ w2a_bot   (no bias; z added in ln2)
  gemm256_kernel<false, false, bf16_t><<<dim3(3, M_/256), 512, 0, stream>>>(
      bufY, w2aBT, nullptr, bufX, nullptr, nullptr);

  // act2 = gelu(LN(h2partial + z[seg]) * g2 + beta2)
  ln2_kernel<<<M_ / 4, 256, 0, stream>>>(bufX, zbuf, seg, g2, beta2, bufY);

  // raw = act2 @ w2b + b2b (fp32 -> d_out); fused segmax -> rmax
  gemm256_kernel<true, true, float><<<dim3(3, M_/256), 512, 0, stream>>>(
      bufY, w2bT, b2b, raw_out, seg, rmax);

  // out = unmap(rmax) + pos_embed
  final2_kernel<<<(B_ * P_ * D_) / (4 * 256), 256, 0, stream>>>(
      (const uint4*)rmax, (const float4*)pos_embed, (float4*)out_f);
}

// Round 5
// 451.061 us; speedup vs baseline: 1.9706x; 1.0129x over previous
//
#include <hip/hip_runtime.h>
#include <hip/hip_bf16.h>
#include <math.h>

#define B_    2
#define NPTS_ 32768
#define T_    32768
#define P_    512
#define C_    4
#define D_    768
#define M_    (B_ * T_)   // 65536

typedef __bf16 bf16_t;
typedef __bf16 bf16x8 __attribute__((ext_vector_type(8)));
typedef __bf16 bf16x4 __attribute__((ext_vector_type(4)));
typedef float  f32x4  __attribute__((ext_vector_type(4)));

__device__ inline void gload16(const void* g, void* l) {
  __builtin_amdgcn_global_load_lds(
      (const __attribute__((address_space(1))) void*)g,
      (__attribute__((address_space(3))) void*)l, 16, 0, 0);
}

__device__ inline float gelu_exact(float x) {
  return 0.5f * x * (1.0f + erff(x * 0.70710678118654752f));
}

// order-preserving float <-> uint map (for atomicMax on floats)
__device__ inline unsigned fmap(float x) {
  unsigned u = __float_as_uint(x);
  return (u & 0x80000000u) ? ~u : (u | 0x80000000u);
}
__device__ inline float funmap(unsigned u) {
  unsigned v = (u & 0x80000000u) ? (u & 0x7FFFFFFFu) : ~u;
  return __uint_as_float(v);
}

// ---------------- seg[t] = segment id via binary search ----------------
__global__ void seg_kernel(const int* __restrict__ off, int* __restrict__ seg) {
  int t = blockIdx.x * blockDim.x + threadIdx.x;
  if (t >= T_) return;
  int lo = 0, hi = P_;
  while (lo < hi) {
    int mid = (lo + hi) >> 1;
    if (off[mid + 1] <= t) lo = mid + 1; else hi = mid;
  }
  seg[t] = lo;
}

// ---------------- zero the two uint-max buffers (adjacent) --------------
__global__ __launch_bounds__(256) void init_umax_kernel(uint4* __restrict__ u) {
  u[blockIdx.x * 256 + threadIdx.x] = make_uint4(0, 0, 0, 0);
}

// ---------------- unmap ymax -> bf16 y ---------------------------------
__global__ __launch_bounds__(256) void yconv_kernel(
    const uint4* __restrict__ ymax, bf16_t* __restrict__ y) {
  int t = blockIdx.x * 256 + threadIdx.x;   // 196608 total
  uint4 u = ymax[t];
  bf16x4 o;
  o[0] = (bf16_t)funmap(u.x); o[1] = (bf16_t)funmap(u.y);
  o[2] = (bf16_t)funmap(u.z); o[3] = (bf16_t)funmap(u.w);
  *(bf16x4*)(y + (size_t)t * 4) = o;
}

// ---------------- unmap rmax + pos_embed -> out fp32 -------------------
__global__ __launch_bounds__(256) void final2_kernel(
    const uint4* __restrict__ rmax, const float4* __restrict__ pe,
    float4* __restrict__ out) {
  int t = blockIdx.x * 256 + threadIdx.x;   // 196608 total
  int row = t / 192, col = t % 192;         // 768/4 = 192
  uint4 u = rmax[t];
  float4 p = pe[(row & (P_ - 1)) * 192 + col];
  float4 o;
  o.x = funmap(u.x) + p.x; o.y = funmap(u.y) + p.y;
  o.z = funmap(u.z) + p.z; o.w = funmap(u.w) + p.w;
  out[t] = o;
}

// ---- weight transpose fp32 [K][N] -> bf16 [N][K], LDS-tiled coalesced ----
__global__ __launch_bounds__(256) void wconvT_kernel(
    const float* __restrict__ src, bf16_t* __restrict__ dst, int K, int N) {
  __shared__ float tile[32][33];
  int n0 = blockIdx.x * 32, k0 = blockIdx.y * 32;
  int tx = threadIdx.x, ty = threadIdx.y;   // 32 x 8
  #pragma unroll
  for (int i = 0; i < 4; ++i)
    tile[ty + 8 * i][tx] = src[(size_t)(k0 + ty + 8 * i) * N + n0 + tx];
  __syncthreads();
  #pragma unroll
  for (int i = 0; i < 4; ++i)
    dst[(size_t)(n0 + ty + 8 * i) * K + k0 + tx] = (bf16_t)tile[tx][ty + 8 * i];
}

// -------- fused: gather latent -> @w1a + b1a -> LN(1e-6) -> gelu -> bf16
__global__ __launch_bounds__(256) void embed_kernel(
    const float4* __restrict__ latent4, const int* __restrict__ pidx,
    const float* __restrict__ w1a, const float* __restrict__ b1a,
    bf16_t* __restrict__ act1) {
  int wid = threadIdx.x >> 6, lane = threadIdx.x & 63;
  int m = blockIdx.x * 4 + wid;
  int b = m >> 15, t = m & (T_ - 1);
  float4 x = latent4[(size_t)b * NPTS_ + pidx[t]];
  int d8 = lane * 8, d4 = 512 + lane * 4;
  float v[12];
  {
    float4 a0 = *(const float4*)(b1a + d8);
    float4 a1 = *(const float4*)(b1a + d8 + 4);
    float4 a2 = *(const float4*)(b1a + d4);
    v[0]=a0.x; v[1]=a0.y; v[2]=a0.z; v[3]=a0.w;
    v[4]=a1.x; v[5]=a1.y; v[6]=a1.z; v[7]=a1.w;
    v[8]=a2.x; v[9]=a2.y; v[10]=a2.z; v[11]=a2.w;
  }
  float xk[4] = {x.x, x.y, x.z, x.w};
  #pragma unroll
  for (int k = 0; k < 4; ++k) {
    const float* w = w1a + k * D_;
    float4 w0 = *(const float4*)(w + d8);
    float4 w1 = *(const float4*)(w + d8 + 4);
    float4 w2 = *(const float4*)(w + d4);
    float f = xk[k];
    v[0] += f*w0.x; v[1] += f*w0.y; v[2] += f*w0.z; v[3] += f*w0.w;
    v[4] += f*w1.x; v[5] += f*w1.y; v[6] += f*w1.z; v[7] += f*w1.w;
    v[8] += f*w2.x; v[9] += f*w2.y; v[10]+= f*w2.z; v[11]+= f*w2.w;
  }
  float sum = 0.f, sq = 0.f;
  #pragma unroll
  for (int j = 0; j < 12; ++j) { sum += v[j]; sq += v[j]*v[j]; }
  #pragma unroll
  for (int o = 32; o > 0; o >>= 1) { sum += __shfl_xor(sum, o); sq += __shfl_xor(sq, o); }
  float mu = sum * (1.0f / D_);
  float rstd = rsqrtf(sq * (1.0f / D_) - mu * mu + 1e-6f);
  bf16x8 o8; bf16x4 o4;
  #pragma unroll
  for (int j = 0; j < 8; ++j) o8[j] = (bf16_t)gelu_exact((v[j] - mu) * rstd);
  #pragma unroll
  for (int j = 0; j < 4; ++j) o4[j] = (bf16_t)gelu_exact((v[8 + j] - mu) * rstd);
  size_t base = (size_t)m * D_;
  *(bf16x8*)(act1 + base + d8) = o8;
  *(bf16x4*)(act1 + base + d4) = o4;
}

// ---- h2 = h2partial + z[seg]; LN(1e-5, g2, beta2) + gelu -> bf16 -------
__global__ __launch_bounds__(256) void ln2_kernel(
    const bf16_t* __restrict__ h2pre, const float* __restrict__ z,
    const int* __restrict__ seg, const float* __restrict__ g2,
    const float* __restrict__ beta2, bf16_t* __restrict__ act2) {
  int wid = threadIdx.x >> 6, lane = threadIdx.x & 63;
  int m = blockIdx.x * 4 + wid;
  int b = m >> 15, t = m & (T_ - 1);
  int d8 = lane * 8, d4 = 512 + lane * 4;
  size_t base = (size_t)m * D_;
  const float* zrow = z + (size_t)((b << 9) + seg[t]) * D_;
  bf16x8 i8 = *(const bf16x8*)(h2pre + base + d8);
  bf16x4 i4 = *(const bf16x4*)(h2pre + base + d4);
  float4 z0 = *(const float4*)(zrow + d8);
  float4 z1 = *(const float4*)(zrow + d8 + 4);
  float4 z2 = *(const float4*)(zrow + d4);
  float v[12];
  #pragma unroll
  for (int j = 0; j < 8; ++j) v[j] = (float)i8[j];
  #pragma unroll
  for (int j = 0; j < 4; ++j) v[8 + j] = (float)i4[j];
  v[0]+=z0.x; v[1]+=z0.y; v[2]+=z0.z; v[3]+=z0.w;
  v[4]+=z1.x; v[5]+=z1.y; v[6]+=z1.z; v[7]+=z1.w;
  v[8]+=z2.x; v[9]+=z2.y; v[10]+=z2.z; v[11]+=z2.w;
  float sum = 0.f, sq = 0.f;
  #pragma unroll
  for (int j = 0; j < 12; ++j) { sum += v[j]; sq += v[j]*v[j]; }
  #pragma unroll
  for (int o = 32; o > 0; o >>= 1) { sum += __shfl_xor(sum, o); sq += __shfl_xor(sq, o); }
  float mu = sum * (1.0f / D_);
  float rstd = rsqrtf(sq * (1.0f / D_) - mu * mu + 1e-5f);
  float4 ga = *(const float4*)(g2 + d8);
  float4 gb = *(const float4*)(g2 + d8 + 4);
  float4 gc = *(const float4*)(g2 + d4);
  float4 ba = *(const float4*)(beta2 + d8);
  float4 bb = *(const float4*)(beta2 + d8 + 4);
  float4 bc = *(const float4*)(beta2 + d4);
  float g[12] = {ga.x,ga.y,ga.z,ga.w, gb.x,gb.y,gb.z,gb.w, gc.x,gc.y,gc.z,gc.w};
  float be[12]= {ba.x,ba.y,ba.z,ba.w, bb.x,bb.y,bb.z,bb.w, bc.x,bc.y,bc.z,bc.w};
  bf16x8 o8; bf16x4 o4;
  #pragma unroll
  for (int j = 0; j < 8; ++j) o8[j] = (bf16_t)gelu_exact((v[j] - mu) * rstd * g[j] + be[j]);
  #pragma unroll
  for (int j = 0; j < 4; ++j) o4[j] = (bf16_t)gelu_exact((v[8+j] - mu) * rstd * g[8+j] + be[8+j]);
  *(bf16x8*)(act2 + base + d8) = o8;
  *(bf16x4*)(act2 + base + d4) = o4;
}

// ===== 256x256 4-phase read-ahead MFMA GEMM (T2+T3+T4+T5), K=N=768 ======
// Every phase issues the ds_reads feeding the NEXT phase's MFMA cluster, so
// lgkm waits are covered by a barrier + 16 MFMAs. 4 barriers + 1 counted
// vmcnt per K-tile. Stage A[j+2] at P2, B[j+2] at P3 (each after the barrier
// that retires the last reader of the slot it overwrites).
#define STAGE_A(P2, KTG)                                                     \
  { _Pragma("unroll")                                                        \
    for (int h = 0; h < 2; ++h) {                                            \
      _Pragma("unroll")                                                      \
      for (int ps = 0; ps < 2; ++ps) {                                       \
        int c = ps * 512 + wid * 64 + lane;                                  \
        int rw = c >> 3;                                                     \
        int cs = (c & 7) ^ (rw & 7);                                         \
        gload16(A + (size_t)(m0 + h * 128 + rw) * 768 + (KTG) + cs * 8,      \
                lds + (P2) * 65536 + h * 16384 + ps * 8192 + wid * 1024);    \
      } } }

#define STAGE_B(P2, KTG)                                                     \
  { _Pragma("unroll")                                                        \
    for (int h = 0; h < 2; ++h) {                                            \
      _Pragma("unroll")                                                      \
      for (int ps = 0; ps < 2; ++ps) {                                       \
        int c = ps * 512 + wid * 64 + lane;                                  \
        int rw = c >> 3;                                                     \
        int cs = (c & 7) ^ (rw & 7);                                         \
        gload16(BT + (size_t)(n0 + h * 128 + rw) * 768 + (KTG) + cs * 8,     \
                lds + (P2) * 65536 + 32768 + h * 16384 + ps * 8192 + wid * 1024); \
      } } }

#define READ_AF0(BASE)                                                       \
  { _Pragma("unroll")                                                        \
    for (int i = 0; i < 4; ++i) {                                            \
      _Pragma("unroll")                                                      \
      for (int s = 0; s < 2; ++s) {                                          \
        int row = i * 16 + lr;                                               \
        int ch = (s * 4 + hi) ^ cx;                                          \
        af0[i][s] = *(const bf16x8*)((BASE) + wm * 16384 + row * 128 + ch * 16); \
      } } }

#define READ_BF0(BASE)                                                       \
  { _Pragma("unroll")                                                        \
    for (int jb = 0; jb < 2; ++jb) {                                         \
      _Pragma("unroll")                                                      \
      for (int s = 0; s < 2; ++s) {                                          \
        int nrow = wn * 64 + jb * 16 + lr;                                   \
        int ch = (s * 4 + hi) ^ cx;                                          \
        bf0[jb][s] = *(const bf16x8*)((BASE) + 32768 + (nrow >> 7) * 16384 + \
                                      (nrow & 127) * 128 + ch * 16);         \
      } } }

template <bool HASBIAS, bool SEGMAX, typename OutT>
__global__ __launch_bounds__(512, 1) void gemm256_kernel(
    const bf16_t* __restrict__ A, const bf16_t* __restrict__ BT,
    const float* __restrict__ bias, OutT* __restrict__ C,
    const int* __restrict__ seg, unsigned* __restrict__ gmax) {
  constexpr int NT = 12;                 // 768 / 64
  __shared__ __align__(16) char lds[131072];
  __shared__ int segm[256];
  int tid = threadIdx.x;
  int wid = tid >> 6, lane = tid & 63;
  int lr = lane & 15, hi = lane >> 4;
  int wm = wid >> 2, wn = wid & 3;

  int gx = gridDim.x;                    // 3
  int nb = gx * gridDim.y;
  int bid = blockIdx.y * gx + blockIdx.x;
  int w = ((nb & 7) == 0) ? ((bid & 7) * (nb >> 3) + (bid >> 3)) : bid;
  int bx = w % gx, by = w / gx;
  int n0 = bx * 256, m0 = by * 256;

  if (SEGMAX) { if (tid < 256) segm[tid] = seg[(m0 + tid) & (T_ - 1)]; }

  f32x4 acc[8][4] = {};
  bf16x8 af0[4][2], af1[4][2], bf0[2][2], bf1[2][2];
  int cx = lr & 7;

  // prologue: stage K-tiles 0 and 1; gate tile 0; pre-read af0/bf0 of tile 0
  STAGE_A(0, 0); STAGE_B(0, 0);
  STAGE_A(1, 64); STAGE_B(1, 64);
  asm volatile("s_waitcnt vmcnt(8)" ::: "memory");
  __builtin_amdgcn_s_barrier();
  READ_AF0(lds); READ_BF0(lds);

  for (int j = 0; j < NT; ++j) {
    const char* base  = lds + (j & 1) * 65536;
    const char* baseN = lds + ((j & 1) ^ 1) * 65536;

    // ---- P0: read af1(j); MFMA Q00 (af0,bf0 read last phase) ----
    #pragma unroll
    for (int i = 0; i < 4; ++i)
      #pragma unroll
      for (int s = 0; s < 2; ++s) {
        int row = 64 + i * 16 + lr;
        int ch = (s * 4 + hi) ^ cx;
        af1[i][s] = *(const bf16x8*)(base + wm * 16384 + row * 128 + ch * 16);
      }
    __builtin_amdgcn_s_setprio(1);
    #pragma unroll
    for (int i = 0; i < 4; ++i)
      #pragma unroll
      for (int jb = 0; jb < 2; ++jb)
        #pragma unroll
        for (int s = 0; s < 2; ++s)
          acc[i][jb] = __builtin_amdgcn_mfma_f32_16x16x32_bf16(af0[i][s], bf0[jb][s], acc[i][jb], 0, 0, 0);
    __builtin_amdgcn_s_setprio(0);
    __builtin_amdgcn_s_barrier();

    // ---- P1: read bf1(j); MFMA Q10 ----
    #pragma unroll
    for (int jb = 0; jb < 2; ++jb)
      #pragma unroll
      for (int s = 0; s < 2; ++s) {
        int nrow = wn * 64 + 32 + jb * 16 + lr;
        int ch = (s * 4 + hi) ^ cx;
        bf1[jb][s] = *(const bf16x8*)(base + 32768 + (nrow >> 7) * 16384 +
                                      (nrow & 127) * 128 + ch * 16);
      }
    __builtin_amdgcn_s_setprio(1);
    #pragma unroll
    for (int i = 0; i < 4; ++i)
      #pragma unroll
      for (int jb = 0; jb < 2; ++jb)
        #pragma unroll
        for (int s = 0; s < 2; ++s)
          acc[4 + i][jb] = __builtin_amdgcn_mfma_f32_16x16x32_bf16(af1[i][s], bf0[jb][s], acc[4 + i][jb], 0, 0, 0);
    __builtin_amdgcn_s_setprio(0);
    __builtin_amdgcn_s_barrier();

    // ---- P2: stage A(j+2) (A(j) readers retired at end-P1); MFMA Q01 ----
    if (j + 2 < NT) STAGE_A(j & 1, (j + 2) * 64);
    __builtin_amdgcn_s_setprio(1);
    #pragma unroll
    for (int i = 0; i < 4; ++i)
      #pragma unroll
      for (int jb = 0; jb < 2; ++jb)
        #pragma unroll
        for (int s = 0; s < 2; ++s)
          acc[i][2 + jb] = __builtin_amdgcn_mfma_f32_16x16x32_bf16(af0[i][s], bf1[jb][s], acc[i][2 + jb], 0, 0, 0);
    __builtin_amdgcn_s_setprio(0);

    // ---- P3: gate tile j+1; read af0/bf0(j+1); stage B(j+2); MFMA Q11 ----
    if (j + 1 < NT) {
      if (j + 2 < NT) asm volatile("s_waitcnt vmcnt(4)" ::: "memory");
      else            asm volatile("s_waitcnt vmcnt(0)" ::: "memory");
      __builtin_amdgcn_s_barrier();   // all waves: tile j+1 landed, B(j) dead
      READ_AF0(baseN); READ_BF0(baseN);
      if (j + 2 < NT) STAGE_B(j & 1, (j + 2) * 64);
    }
    __builtin_amdgcn_s_setprio(1);
    #pragma unroll
    for (int i = 0; i < 4; ++i)
      #pragma unroll
      for (int jb = 0; jb < 2; ++jb)
        #pragma unroll
        for (int s = 0; s < 2; ++s)
          acc[4 + i][2 + jb] = __builtin_amdgcn_mfma_f32_16x16x32_bf16(af1[i][s], bf1[jb][s], acc[4 + i][2 + jb], 0, 0, 0);
    __builtin_amdgcn_s_setprio(0);
    __builtin_amdgcn_s_barrier();
  }

  // ---- epilogue: bias + C store + fused segmax ----
  unsigned* smax = reinterpret_cast<unsigned*>(lds);
  int sb = 0, zb = 0;
  if (SEGMAX) {
    sb = segm[0];
    zb = (m0 >> 15) << 9;                // batch * 512
    for (int q = tid; q < 16 * 256; q += 512) smax[q] = 0u;
    __syncthreads();
  }

  #pragma unroll
  for (int jn = 0; jn < 4; ++jn) {
    int nl = wn * 64 + jn * 16 + lr;
    int n = n0 + nl;
    float bv = HASBIAS ? bias[n] : 0.f;
    #pragma unroll
    for (int i = 0; i < 8; ++i) {
      int rb = wm * 128 + i * 16 + hi * 4;
      float vv[4];
      #pragma unroll
      for (int r = 0; r < 4; ++r) {
        vv[r] = acc[i][jn][r] + bv;
        C[(size_t)(m0 + rb + r) * 768 + n] = (OutT)vv[r];
      }
      if (SEGMAX) {
        int sA = segm[rb] - sb, sB = segm[rb + 3] - sb;
        if (sA == sB) {
          float mx = fmaxf(fmaxf(vv[0], vv[1]), fmaxf(vv[2], vv[3]));
          atomicMax(&smax[sA * 256 + nl], fmap(mx));
        } else {
          #pragma unroll
          for (int r = 0; r < 4; ++r)
            atomicMax(&smax[(segm[rb + r] - sb) * 256 + nl], fmap(vv[r]));
        }
      }
    }
  }

  if (SEGMAX) {
    __syncthreads();
    int nseg = segm[255] - sb + 1;
    for (int q = tid; q < nseg * 256; q += 512) {
      int sl = q >> 8, nl2 = q & 255;
      atomicMax(&gmax[(size_t)(zb + sb + sl) * 768 + n0 + nl2], smax[q]);
    }
  }
}

extern "C" void kernel_launch(void* const* d_in, const int* in_sizes, int n_in,
                              void* d_out, int out_size, void* d_ws, size_t ws_size,
                              hipStream_t stream) {
  const float* latent       = (const float*)d_in[0];
  const int*   patch_index  = (const int*)d_in[1];
  const int*   patch_offset = (const int*)d_in[2];
  const float* pos_embed    = (const float*)d_in[3];
  const float* w1a  = (const float*)d_in[4];
  const float* b1a  = (const float*)d_in[5];
  const float* w1b  = (const float*)d_in[6];
  const float* b1b  = (const float*)d_in[7];
  const float* w2a  = (const float*)d_in[8];
  const float* b2a  = (const float*)d_in[9];
  const float* g2   = (const float*)d_in[10];
  const float* beta2= (const float*)d_in[11];
  const float* w2b  = (const float*)d_in[12];
  const float* b2b  = (const float*)d_in[13];

  float* out_f   = (float*)d_out;
  float* raw_out = out_f + (size_t)B_ * P_ * D_;

  char* ws = (char*)d_ws;
  size_t off = 0;
  auto take = [&](size_t bytes) {
    off = (off + 255) & ~(size_t)255;
    char* p = ws + off;
    off += bytes;
    return p;
  };
  int*      seg   = (int*)     take((size_t)T_ * 4);
  bf16_t*   w1bT  = (bf16_t*)  take((size_t)D_ * D_ * 2);
  bf16_t*   w2aTT = (bf16_t*)  take((size_t)D_ * D_ * 2);
  bf16_t*   w2aBT = (bf16_t*)  take((size_t)D_ * D_ * 2);
  bf16_t*   w2bT  = (bf16_t*)  take((size_t)D_ * D_ * 2);
  bf16_t*   ybuf  = (bf16_t*)  take((size_t)B_ * P_ * D_ * 2);
  float*    zbuf  = (float*)   take((size_t)B_ * P_ * D_ * 4);
  unsigned* umax  = (unsigned*)take((size_t)2 * B_ * P_ * D_ * 4);  // ymax|rmax
  unsigned* ymax  = umax;
  unsigned* rmax  = umax + (size_t)B_ * P_ * D_;
  bf16_t*   bufY  = (bf16_t*)  take((size_t)M_ * D_ * 2);
  size_t needX = (size_t)M_ * D_ * 2;
  size_t offX  = (off + 255) & ~(size_t)255;
  bf16_t* bufX;
  if (offX + needX <= ws_size) {
    bufX = (bf16_t*)take(needX);
  } else {
    bufX = (bf16_t*)raw_out;  // dead before gemm4 overwrites with real raw
  }

  seg_kernel<<<(T_ + 255) / 256, 256, 0, stream>>>(patch_offset, seg);
  init_umax_kernel<<<(2 * B_ * P_ * D_) / (4 * 256), 256, 0, stream>>>((uint4*)umax);
  dim3 wcb(32, 8);
  wconvT_kernel<<<dim3(D_/32, D_/32), wcb, 0, stream>>>(w1b, w1bT, D_, D_);
  wconvT_kernel<<<dim3(D_/32, D_/32), wcb, 0, stream>>>(w2a, w2aTT, D_, D_);
  wconvT_kernel<<<dim3(D_/32, D_/32), wcb, 0, stream>>>(w2a + (size_t)D_*D_, w2aBT, D_, D_);
  wconvT_kernel<<<dim3(D_/32, D_/32), wcb, 0, stream>>>(w2b, w2bT, D_, D_);

  // act1 = gelu(LN(latent[pidx] @ w1a + b1a))
  embed_kernel<<<M_ / 4, 256, 0, stream>>>((const float4*)latent, patch_index, w1a, b1a, bufX);

  // h = act1 @ w1b + b1b; fused y = segmax(h) -> ymax
  gemm256_kernel<true, true, bf16_t><<<dim3(3, M_/256), 512, 0, stream>>>(
      bufX, w1bT, b1b, bufY, seg, ymax);

  // y bf16
  yconv_kernel<<<(B_ * P_ * D_) / (4 * 256), 256, 0, stream>>>((const uint4*)ymax, ybuf);

  // z = y @ w2a_top + b2a   (1024 x 768 x 768, fp32 out)
  gemm256_kernel<true, false, float><<<dim3(3, (B_*P_)/256), 512, 0, stream>>>(
      ybuf, w2aTT, b2a, zbuf, nullptr, nullptr);

  // h2partial = h @ w2a_bot   (no bias; z added in ln2)
  gemm256_kernel<false, false, bf16_t><<<dim3(3, M_/256), 512, 0, stream>>>(
      bufY, w2aBT, nullptr, bufX, nullptr, nullptr);

  // act2 = gelu(LN(h2partial + z[seg]) * g2 + beta2)
  ln2_kernel<<<M_ / 4, 256, 0, stream>>>(bufX, zbuf, seg, g2, beta2, bufY);

  // raw = act2 @ w2b + b2b (fp32 -> d_out); fused segmax -> rmax
  gemm256_kernel<true, true, float><<<dim3(3, M_/256), 512, 0, stream>>>(
      bufY, w2bT, b2b, raw_out, seg, rmax);

  // out = unmap(rmax) + pos_embed
  final2_kernel<<<(B_ * P_ * D_) / (4 * 256), 256, 0, stream>>>(
      (const uint4*)rmax, (const float4*)pos_embed, (float4*)out_f);
}

// Round 6
// 438.446 us; speedup vs baseline: 2.0273x; 1.0288x over previous
//
#include <hip/hip_runtime.h>
#include <hip/hip_bf16.h>
#include <math.h>

#define B_    2
#define NPTS_ 32768
#define T_    32768
#define P_    512
#define C_    4
#define D_    768
#define M_    (B_ * T_)   // 65536

typedef __bf16 bf16_t;
typedef __bf16 bf16x8 __attribute__((ext_vector_type(8)));
typedef __bf16 bf16x4 __attribute__((ext_vector_type(4)));
typedef float  f32x4  __attribute__((ext_vector_type(4)));

__device__ inline void gload16(const void* g, void* l) {
  __builtin_amdgcn_global_load_lds(
      (const __attribute__((address_space(1))) void*)g,
      (__attribute__((address_space(3))) void*)l, 16, 0, 0);
}

__device__ inline float gelu_exact(float x) {
  return 0.5f * x * (1.0f + erff(x * 0.70710678118654752f));
}

// order-preserving float <-> uint map (for atomicMax on floats)
__device__ inline unsigned fmap(float x) {
  unsigned u = __float_as_uint(x);
  return (u & 0x80000000u) ? ~u : (u | 0x80000000u);
}
__device__ inline float funmap(unsigned u) {
  unsigned v = (u & 0x80000000u) ? (u & 0x7FFFFFFFu) : ~u;
  return __uint_as_float(v);
}

// ---- fused prep: 4x weight transpose + seg binary search + umax zero ----
// blocks [0,2304): weight transpose (576 each for w1b, w2aT, w2aB, w2b)
// blocks [2304,2432): seg[t]  (T_=32768 / 256)
// blocks [2432,3968): zero umax (1536 * 256 uint4)
__global__ __launch_bounds__(256) void prep_kernel(
    const int* __restrict__ off, int* __restrict__ seg, uint4* __restrict__ umax,
    const float* __restrict__ w1b, const float* __restrict__ w2a,
    const float* __restrict__ w2b,
    bf16_t* __restrict__ w1bT, bf16_t* __restrict__ w2aTT,
    bf16_t* __restrict__ w2aBT, bf16_t* __restrict__ w2bT) {
  __shared__ float tile[32][33];
  int bid = blockIdx.x, tid = threadIdx.x;
  if (bid < 2304) {
    const float* src; bf16_t* dst;
    int which = bid / 576, r = bid - which * 576;
    if (which == 0)      { src = w1b;             dst = w1bT;  }
    else if (which == 1) { src = w2a;             dst = w2aTT; }
    else if (which == 2) { src = w2a + D_ * D_;   dst = w2aBT; }
    else                 { src = w2b;             dst = w2bT;  }
    int n0 = (r % 24) * 32, k0 = (r / 24) * 32;
    int tx = tid & 31, ty = tid >> 5;
    #pragma unroll
    for (int i = 0; i < 4; ++i)
      tile[ty + 8 * i][tx] = src[(size_t)(k0 + ty + 8 * i) * D_ + n0 + tx];
    __syncthreads();
    #pragma unroll
    for (int i = 0; i < 4; ++i)
      dst[(size_t)(n0 + ty + 8 * i) * D_ + k0 + tx] = (bf16_t)tile[tx][ty + 8 * i];
  } else if (bid < 2432) {
    int t = (bid - 2304) * 256 + tid;
    int lo = 0, hi = P_;
    while (lo < hi) {
      int mid = (lo + hi) >> 1;
      if (off[mid + 1] <= t) lo = mid + 1; else hi = mid;
    }
    seg[t] = lo;
  } else {
    umax[(size_t)(bid - 2432) * 256 + tid] = make_uint4(0, 0, 0, 0);
  }
}

// ---------------- unmap ymax -> bf16 y ---------------------------------
__global__ __launch_bounds__(256) void yconv_kernel(
    const uint4* __restrict__ ymax, bf16_t* __restrict__ y) {
  int t = blockIdx.x * 256 + threadIdx.x;   // 196608 total
  uint4 u = ymax[t];
  bf16x4 o;
  o[0] = (bf16_t)funmap(u.x); o[1] = (bf16_t)funmap(u.y);
  o[2] = (bf16_t)funmap(u.z); o[3] = (bf16_t)funmap(u.w);
  *(bf16x4*)(y + (size_t)t * 4) = o;
}

// ---------------- unmap rmax + pos_embed -> out fp32 -------------------
__global__ __launch_bounds__(256) void final2_kernel(
    const uint4* __restrict__ rmax, const float4* __restrict__ pe,
    float4* __restrict__ out) {
  int t = blockIdx.x * 256 + threadIdx.x;   // 196608 total
  int row = t / 192, col = t % 192;         // 768/4 = 192
  uint4 u = rmax[t];
  float4 p = pe[(row & (P_ - 1)) * 192 + col];
  float4 o;
  o.x = funmap(u.x) + p.x; o.y = funmap(u.y) + p.y;
  o.z = funmap(u.z) + p.z; o.w = funmap(u.w) + p.w;
  out[t] = o;
}

// -------- fused: gather latent -> @w1a + b1a -> LN(1e-6) -> gelu -> bf16
__global__ __launch_bounds__(256) void embed_kernel(
    const float4* __restrict__ latent4, const int* __restrict__ pidx,
    const float* __restrict__ w1a, const float* __restrict__ b1a,
    bf16_t* __restrict__ act1) {
  int wid = threadIdx.x >> 6, lane = threadIdx.x & 63;
  int m = blockIdx.x * 4 + wid;
  int b = m >> 15, t = m & (T_ - 1);
  float4 x = latent4[(size_t)b * NPTS_ + pidx[t]];
  int d8 = lane * 8, d4 = 512 + lane * 4;
  float v[12];
  {
    float4 a0 = *(const float4*)(b1a + d8);
    float4 a1 = *(const float4*)(b1a + d8 + 4);
    float4 a2 = *(const float4*)(b1a + d4);
    v[0]=a0.x; v[1]=a0.y; v[2]=a0.z; v[3]=a0.w;
    v[4]=a1.x; v[5]=a1.y; v[6]=a1.z; v[7]=a1.w;
    v[8]=a2.x; v[9]=a2.y; v[10]=a2.z; v[11]=a2.w;
  }
  float xk[4] = {x.x, x.y, x.z, x.w};
  #pragma unroll
  for (int k = 0; k < 4; ++k) {
    const float* w = w1a + k * D_;
    float4 w0 = *(const float4*)(w + d8);
    float4 w1 = *(const float4*)(w + d8 + 4);
    float4 w2 = *(const float4*)(w + d4);
    float f = xk[k];
    v[0] += f*w0.x; v[1] += f*w0.y; v[2] += f*w0.z; v[3] += f*w0.w;
    v[4] += f*w1.x; v[5] += f*w1.y; v[6] += f*w1.z; v[7] += f*w1.w;
    v[8] += f*w2.x; v[9] += f*w2.y; v[10]+= f*w2.z; v[11]+= f*w2.w;
  }
  float sum = 0.f, sq = 0.f;
  #pragma unroll
  for (int j = 0; j < 12; ++j) { sum += v[j]; sq += v[j]*v[j]; }
  #pragma unroll
  for (int o = 32; o > 0; o >>= 1) { sum += __shfl_xor(sum, o); sq += __shfl_xor(sq, o); }
  float mu = sum * (1.0f / D_);
  float rstd = rsqrtf(sq * (1.0f / D_) - mu * mu + 1e-6f);
  bf16x8 o8; bf16x4 o4;
  #pragma unroll
  for (int j = 0; j < 8; ++j) o8[j] = (bf16_t)gelu_exact((v[j] - mu) * rstd);
  #pragma unroll
  for (int j = 0; j < 4; ++j) o4[j] = (bf16_t)gelu_exact((v[8 + j] - mu) * rstd);
  size_t base = (size_t)m * D_;
  *(bf16x8*)(act1 + base + d8) = o8;
  *(bf16x4*)(act1 + base + d4) = o4;
}

// ---- h2 = h2partial + z[seg]; LN(1e-5, g2, beta2) + gelu -> bf16 -------
__global__ __launch_bounds__(256) void ln2_kernel(
    const bf16_t* __restrict__ h2pre, const float* __restrict__ z,
    const int* __restrict__ seg, const float* __restrict__ g2,
    const float* __restrict__ beta2, bf16_t* __restrict__ act2) {
  int wid = threadIdx.x >> 6, lane = threadIdx.x & 63;
  int m = blockIdx.x * 4 + wid;
  int b = m >> 15, t = m & (T_ - 1);
  int d8 = lane * 8, d4 = 512 + lane * 4;
  size_t base = (size_t)m * D_;
  const float* zrow = z + (size_t)((b << 9) + seg[t]) * D_;
  bf16x8 i8 = *(const bf16x8*)(h2pre + base + d8);
  bf16x4 i4 = *(const bf16x4*)(h2pre + base + d4);
  float4 z0 = *(const float4*)(zrow + d8);
  float4 z1 = *(const float4*)(zrow + d8 + 4);
  float4 z2 = *(const float4*)(zrow + d4);
  float v[12];
  #pragma unroll
  for (int j = 0; j < 8; ++j) v[j] = (float)i8[j];
  #pragma unroll
  for (int j = 0; j < 4; ++j) v[8 + j] = (float)i4[j];
  v[0]+=z0.x; v[1]+=z0.y; v[2]+=z0.z; v[3]+=z0.w;
  v[4]+=z1.x; v[5]+=z1.y; v[6]+=z1.z; v[7]+=z1.w;
  v[8]+=z2.x; v[9]+=z2.y; v[10]+=z2.z; v[11]+=z2.w;
  float sum = 0.f, sq = 0.f;
  #pragma unroll
  for (int j = 0; j < 12; ++j) { sum += v[j]; sq += v[j]*v[j]; }
  #pragma unroll
  for (int o = 32; o > 0; o >>= 1) { sum += __shfl_xor(sum, o); sq += __shfl_xor(sq, o); }
  float mu = sum * (1.0f / D_);
  float rstd = rsqrtf(sq * (1.0f / D_) - mu * mu + 1e-5f);
  float4 ga = *(const float4*)(g2 + d8);
  float4 gb = *(const float4*)(g2 + d8 + 4);
  float4 gc = *(const float4*)(g2 + d4);
  float4 ba = *(const float4*)(beta2 + d8);
  float4 bb = *(const float4*)(beta2 + d8 + 4);
  float4 bc = *(const float4*)(beta2 + d4);
  float g[12] = {ga.x,ga.y,ga.z,ga.w, gb.x,gb.y,gb.z,gb.w, gc.x,gc.y,gc.z,gc.w};
  float be[12]= {ba.x,ba.y,ba.z,ba.w, bb.x,bb.y,bb.z,bb.w, bc.x,bc.y,bc.z,bc.w};
  bf16x8 o8; bf16x4 o4;
  #pragma unroll
  for (int j = 0; j < 8; ++j) o8[j] = (bf16_t)gelu_exact((v[j] - mu) * rstd * g[j] + be[j]);
  #pragma unroll
  for (int j = 0; j < 4; ++j) o4[j] = (bf16_t)gelu_exact((v[8+j] - mu) * rstd * g[8+j] + be[8+j]);
  *(bf16x8*)(act2 + base + d8) = o8;
  *(bf16x4*)(act2 + base + d4) = o4;
}

// ===== 256x256 4-phase read-ahead MFMA GEMM (T2+T3+T4+T5), K=N=768 ======
// Fused segmax epilogue: interior segments (fully inside this block's 256
// rows) flush with plain stores; only boundary-straddling segments use
// global atomicMax (cuts ~1M device atomics to ~0.4M -> WRITE_SIZE drop).
#define STAGE_A(P2, KTG)                                                     \
  { _Pragma("unroll")                                                        \
    for (int h = 0; h < 2; ++h) {                                            \
      _Pragma("unroll")                                                      \
      for (int ps = 0; ps < 2; ++ps) {                                       \
        int c = ps * 512 + wid * 64 + lane;                                  \
        int rw = c >> 3;                                                     \
        int cs = (c & 7) ^ (rw & 7);                                         \
        gload16(A + (size_t)(m0 + h * 128 + rw) * 768 + (KTG) + cs * 8,      \
                lds + (P2) * 65536 + h * 16384 + ps * 8192 + wid * 1024);    \
      } } }

#define STAGE_B(P2, KTG)                                                     \
  { _Pragma("unroll")                                                        \
    for (int h = 0; h < 2; ++h) {                                            \
      _Pragma("unroll")                                                      \
      for (int ps = 0; ps < 2; ++ps) {                                       \
        int c = ps * 512 + wid * 64 + lane;                                  \
        int rw = c >> 3;                                                     \
        int cs = (c & 7) ^ (rw & 7);                                         \
        gload16(BT + (size_t)(n0 + h * 128 + rw) * 768 + (KTG) + cs * 8,     \
                lds + (P2) * 65536 + 32768 + h * 16384 + ps * 8192 + wid * 1024); \
      } } }

#define READ_AF0(BASE)                                                       \
  { _Pragma("unroll")                                                        \
    for (int i = 0; i < 4; ++i) {                                            \
      _Pragma("unroll")                                                      \
      for (int s = 0; s < 2; ++s) {                                          \
        int row = i * 16 + lr;                                               \
        int ch = (s * 4 + hi) ^ cx;                                          \
        af0[i][s] = *(const bf16x8*)((BASE) + wm * 16384 + row * 128 + ch * 16); \
      } } }

#define READ_BF0(BASE)                                                       \
  { _Pragma("unroll")                                                        \
    for (int jb = 0; jb < 2; ++jb) {                                         \
      _Pragma("unroll")                                                      \
      for (int s = 0; s < 2; ++s) {                                          \
        int nrow = wn * 64 + jb * 16 + lr;                                   \
        int ch = (s * 4 + hi) ^ cx;                                          \
        bf0[jb][s] = *(const bf16x8*)((BASE) + 32768 + (nrow >> 7) * 16384 + \
                                      (nrow & 127) * 128 + ch * 16);         \
      } } }

template <bool HASBIAS, bool SEGMAX, typename OutT>
__global__ __launch_bounds__(512, 1) void gemm256_kernel(
    const bf16_t* __restrict__ A, const bf16_t* __restrict__ BT,
    const float* __restrict__ bias, OutT* __restrict__ C,
    const int* __restrict__ seg, unsigned* __restrict__ gmax) {
  constexpr int NT = 12;                 // 768 / 64
  __shared__ __align__(16) char lds[131072];
  __shared__ int segm[256];
  int tid = threadIdx.x;
  int wid = tid >> 6, lane = tid & 63;
  int lr = lane & 15, hi = lane >> 4;
  int wm = wid >> 2, wn = wid & 3;

  int gx = gridDim.x;                    // 3
  int nb = gx * gridDim.y;
  int bid = blockIdx.y * gx + blockIdx.x;
  int w = ((nb & 7) == 0) ? ((bid & 7) * (nb >> 3) + (bid >> 3)) : bid;
  int bx = w % gx, by = w / gx;
  int n0 = bx * 256, m0 = by * 256;

  if (SEGMAX) { if (tid < 256) segm[tid] = seg[(m0 + tid) & (T_ - 1)]; }

  f32x4 acc[8][4] = {};
  bf16x8 af0[4][2], af1[4][2], bf0[2][2], bf1[2][2];
  int cx = lr & 7;

  // prologue: stage K-tiles 0 and 1; gate tile 0; pre-read af0/bf0 of tile 0
  STAGE_A(0, 0); STAGE_B(0, 0);
  STAGE_A(1, 64); STAGE_B(1, 64);
  asm volatile("s_waitcnt vmcnt(8)" ::: "memory");
  __builtin_amdgcn_s_barrier();
  READ_AF0(lds); READ_BF0(lds);

  for (int j = 0; j < NT; ++j) {
    const char* base  = lds + (j & 1) * 65536;
    const char* baseN = lds + ((j & 1) ^ 1) * 65536;

    // ---- P0: read af1(j); MFMA Q00 (af0,bf0 read last phase) ----
    #pragma unroll
    for (int i = 0; i < 4; ++i)
      #pragma unroll
      for (int s = 0; s < 2; ++s) {
        int row = 64 + i * 16 + lr;
        int ch = (s * 4 + hi) ^ cx;
        af1[i][s] = *(const bf16x8*)(base + wm * 16384 + row * 128 + ch * 16);
      }
    __builtin_amdgcn_s_setprio(1);
    #pragma unroll
    for (int i = 0; i < 4; ++i)
      #pragma unroll
      for (int jb = 0; jb < 2; ++jb)
        #pragma unroll
        for (int s = 0; s < 2; ++s)
          acc[i][jb] = __builtin_amdgcn_mfma_f32_16x16x32_bf16(af0[i][s], bf0[jb][s], acc[i][jb], 0, 0, 0);
    __builtin_amdgcn_s_setprio(0);
    __builtin_amdgcn_s_barrier();

    // ---- P1: read bf1(j); MFMA Q10 ----
    #pragma unroll
    for (int jb = 0; jb < 2; ++jb)
      #pragma unroll
      for (int s = 0; s < 2; ++s) {
        int nrow = wn * 64 + 32 + jb * 16 + lr;
        int ch = (s * 4 + hi) ^ cx;
        bf1[jb][s] = *(const bf16x8*)(base + 32768 + (nrow >> 7) * 16384 +
                                      (nrow & 127) * 128 + ch * 16);
      }
    __builtin_amdgcn_s_setprio(1);
    #pragma unroll
    for (int i = 0; i < 4; ++i)
      #pragma unroll
      for (int jb = 0; jb < 2; ++jb)
        #pragma unroll
        for (int s = 0; s < 2; ++s)
          acc[4 + i][jb] = __builtin_amdgcn_mfma_f32_16x16x32_bf16(af1[i][s], bf0[jb][s], acc[4 + i][jb], 0, 0, 0);
    __builtin_amdgcn_s_setprio(0);
    __builtin_amdgcn_s_barrier();

    // ---- P2: stage A(j+2) (A(j) readers retired at end-P1); MFMA Q01 ----
    if (j + 2 < NT) STAGE_A(j & 1, (j + 2) * 64);
    __builtin_amdgcn_s_setprio(1);
    #pragma unroll
    for (int i = 0; i < 4; ++i)
      #pragma unroll
      for (int jb = 0; jb < 2; ++jb)
        #pragma unroll
        for (int s = 0; s < 2; ++s)
          acc[i][2 + jb] = __builtin_amdgcn_mfma_f32_16x16x32_bf16(af0[i][s], bf1[jb][s], acc[i][2 + jb], 0, 0, 0);
    __builtin_amdgcn_s_setprio(0);

    // ---- P3: gate tile j+1; read af0/bf0(j+1); stage B(j+2); MFMA Q11 ----
    if (j + 1 < NT) {
      if (j + 2 < NT) asm volatile("s_waitcnt vmcnt(4)" ::: "memory");
      else            asm volatile("s_waitcnt vmcnt(0)" ::: "memory");
      __builtin_amdgcn_s_barrier();   // all waves: tile j+1 landed, B(j) dead
      READ_AF0(baseN); READ_BF0(baseN);
      if (j + 2 < NT) STAGE_B(j & 1, (j + 2) * 64);
    }
    __builtin_amdgcn_s_setprio(1);
    #pragma unroll
    for (int i = 0; i < 4; ++i)
      #pragma unroll
      for (int jb = 0; jb < 2; ++jb)
        #pragma unroll
        for (int s = 0; s < 2; ++s)
          acc[4 + i][2 + jb] = __builtin_amdgcn_mfma_f32_16x16x32_bf16(af1[i][s], bf1[jb][s], acc[4 + i][2 + jb], 0, 0, 0);
    __builtin_amdgcn_s_setprio(0);
    __builtin_amdgcn_s_barrier();
  }

  // ---- epilogue: bias + C store + fused segmax ----
  unsigned* smax = reinterpret_cast<unsigned*>(lds);
  int sb = 0, zb = 0;
  if (SEGMAX) {
    sb = segm[0];
    zb = (m0 >> 15) << 9;                // batch * 512
    for (int q = tid; q < 16 * 256; q += 512) smax[q] = 0u;
    __syncthreads();
  }

  #pragma unroll
  for (int jn = 0; jn < 4; ++jn) {
    int nl = wn * 64 + jn * 16 + lr;
    int n = n0 + nl;
    float bv = HASBIAS ? bias[n] : 0.f;
    #pragma unroll
    for (int i = 0; i < 8; ++i) {
      int rb = wm * 128 + i * 16 + hi * 4;
      float vv[4];
      #pragma unroll
      for (int r = 0; r < 4; ++r) {
        vv[r] = acc[i][jn][r] + bv;
        C[(size_t)(m0 + rb + r) * 768 + n] = (OutT)vv[r];
      }
      if (SEGMAX) {
        int sA = segm[rb] - sb, sB = segm[rb + 3] - sb;
        if (sA == sB) {
          float mx = fmaxf(fmaxf(vv[0], vv[1]), fmaxf(vv[2], vv[3]));
          atomicMax(&smax[sA * 256 + nl], fmap(mx));
        } else {
          #pragma unroll
          for (int r = 0; r < 4; ++r)
            atomicMax(&smax[(segm[rb + r] - sb) * 256 + nl], fmap(vv[r]));
        }
      }
    }
  }

  if (SEGMAX) {
    __syncthreads();
    int nseg = segm[255] - sb + 1;
    int mlo = m0 & (T_ - 1);
    // does first/last segment straddle this block's row range?
    bool strad_lo = (mlo != 0) && (seg[(mlo - 1)] == sb);
    bool strad_hi = (mlo + 256 < T_) && (seg[(mlo + 256)] == segm[255]);
    for (int q = tid; q < nseg * 256; q += 512) {
      int sl = q >> 8, nl2 = q & 255;
      unsigned val = smax[q];
      unsigned* dst = &gmax[(size_t)(zb + sb + sl) * 768 + n0 + nl2];
      bool bdry = (sl == 0 && strad_lo) || (sl == nseg - 1 && strad_hi);
      if (bdry) atomicMax(dst, val);
      else      *dst = val;               // exclusive owner of this segment
    }
  }
}

extern "C" void kernel_launch(void* const* d_in, const int* in_sizes, int n_in,
                              void* d_out, int out_size, void* d_ws, size_t ws_size,
                              hipStream_t stream) {
  const float* latent       = (const float*)d_in[0];
  const int*   patch_index  = (const int*)d_in[1];
  const int*   patch_offset = (const int*)d_in[2];
  const float* pos_embed    = (const float*)d_in[3];
  const float* w1a  = (const float*)d_in[4];
  const float* b1a  = (const float*)d_in[5];
  const float* w1b  = (const float*)d_in[6];
  const float* b1b  = (const float*)d_in[7];
  const float* w2a  = (const float*)d_in[8];
  const float* b2a  = (const float*)d_in[9];
  const float* g2   = (const float*)d_in[10];
  const float* beta2= (const float*)d_in[11];
  const float* w2b  = (const float*)d_in[12];
  const float* b2b  = (const float*)d_in[13];

  float* out_f   = (float*)d_out;
  float* raw_out = out_f + (size_t)B_ * P_ * D_;

  char* ws = (char*)d_ws;
  size_t off = 0;
  auto take = [&](size_t bytes) {
    off = (off + 255) & ~(size_t)255;
    char* p = ws + off;
    off += bytes;
    return p;
  };
  int*      seg   = (int*)     take((size_t)T_ * 4);
  bf16_t*   w1bT  = (bf16_t*)  take((size_t)D_ * D_ * 2);
  bf16_t*   w2aTT = (bf16_t*)  take((size_t)D_ * D_ * 2);
  bf16_t*   w2aBT = (bf16_t*)  take((size_t)D_ * D_ * 2);
  bf16_t*   w2bT  = (bf16_t*)  take((size_t)D_ * D_ * 2);
  bf16_t*   ybuf  = (bf16_t*)  take((size_t)B_ * P_ * D_ * 2);
  float*    zbuf  = (float*)   take((size_t)B_ * P_ * D_ * 4);
  unsigned* umax  = (unsigned*)take((size_t)2 * B_ * P_ * D_ * 4);  // ymax|rmax
  unsigned* ymax  = umax;
  unsigned* rmax  = umax + (size_t)B_ * P_ * D_;
  bf16_t*   bufY  = (bf16_t*)  take((size_t)M_ * D_ * 2);
  size_t needX = (size_t)M_ * D_ * 2;
  size_t offX  = (off + 255) & ~(size_t)255;
  bf16_t* bufX;
  if (offX + needX <= ws_size) {
    bufX = (bf16_t*)take(needX);
  } else {
    bufX = (bf16_t*)raw_out;  // dead before gemm4 overwrites with real raw
  }

  // fused prep: 4 weight transposes + seg + umax zero
  prep_kernel<<<3968, 256, 0, stream>>>(patch_offset, seg, (uint4*)umax,
                                        w1b, w2a, w2b, w1bT, w2aTT, w2aBT, w2bT);

  // act1 = gelu(LN(latent[pidx] @ w1a + b1a))
  embed_kernel<<<M_ / 4, 256, 0, stream>>>((const float4*)latent, patch_index, w1a, b1a, bufX);

  // h = act1 @ w1b + b1b; fused y = segmax(h) -> ymax
  gemm256_kernel<true, true, bf16_t><<<dim3(3, M_/256), 512, 0, stream>>>(
      bufX, w1bT, b1b, bufY, seg, ymax);

  // y bf16
  yconv_kernel<<<(B_ * P_ * D_) / (4 * 256), 256, 0, stream>>>((const uint4*)ymax, ybuf);

  // z = y @ w2a_top + b2a   (1024 x 768 x 768, fp32 out)
  gemm256_kernel<true, false, float><<<dim3(3, (B_*P_)/256), 512, 0, stream>>>(
      ybuf, w2aTT, b2a, zbuf, nullptr, nullptr);

  // h2partial = h @ w2a_bot   (no bias; z added in ln2)
  gemm256_kernel<false, false, bf16_t><<<dim3(3, M_/256), 512, 0, stream>>>(
      bufY, w2aBT, nullptr, bufX, nullptr, nullptr);

  // act2 = gelu(LN(h2partial + z[seg]) * g2 + beta2)
  ln2_kernel<<<M_ / 4, 256, 0, stream>>>(bufX, zbuf, seg, g2, beta2, bufY);

  // raw = act2 @ w2b + b2b (fp32 -> d_out); fused segmax -> rmax
  gemm256_kernel<true, true, float><<<dim3(3, M_/256), 512, 0, stream>>>(
      bufY, w2bT, b2b, raw_out, seg, rmax);

  // out = unmap(rmax) + pos_embed
  final2_kernel<<<(B_ * P_ * D_) / (4 * 256), 256, 0, stream>>>(
      (const uint4*)rmax, (const float4*)pos_embed, (float4*)out_f);
}